// Round 1
// 989.666 us; speedup vs baseline: 1.3102x; 1.3102x over previous
//
#include <hip/hip_runtime.h>
#include <math.h>

// AFNO-3D: rfftn(32^3, ortho) -> blockdiag complex MLP (8 x 96x96, GELU, softshrink) -> irfftn + residual
// B=2, C=768 (8 blocks x 96), H=W=D=32, Dr=17. kept==Dr -> no truncation.
//
// This round: k1 and k5 (previously scalar-fp32 VALU-bound DFT loops, MfmaUtil=0,
// VALUBusy ~88%) rewritten as per-plane MFMA matmuls using split-bf16 (hi+lo)
// operands for fp32-equivalent precision. 72 MFMAs/block; kernels become HBM-bound.

#define CH    768
#define DR    17
#define PLANE 544            // 32*17 (kw,kd) plane elements
#define NVOL  49152          // B*C*H = 2*768*32
#define CSTRIDE 17408        // 32*PLANE, per-channel complex elements
#define ORTHO 0.0055242717280199026f   // 1/sqrt(32768)
#define TWOPI_32 0.19634954084936207f  // 2*pi/32

typedef __bf16 bf16x8 __attribute__((ext_vector_type(8)));
typedef float  f32x4  __attribute__((ext_vector_type(4)));

#define MFMA __builtin_amdgcn_mfma_f32_16x16x32_bf16

__device__ __forceinline__ float gelu_f(float v) {
    return 0.5f * v * (1.0f + erff(v * 0.7071067811865475f));
}
__device__ __forceinline__ float sshrink(float v) {
    float a = fabsf(v) - 0.01f;
    return a > 0.f ? copysignf(a, v) : 0.f;
}
__device__ __forceinline__ bf16x8 ld8(const __bf16* p) { return *(const bf16x8*)p; }
// split v into bf16 hi + bf16 lo so hi+lo carries ~17 mantissa bits (fp32-equivalent
// through a 3-product MFMA: Ah*Bh + Ah*Bl + Al*Bh; dropped Al*Bl ~ 2^-18 relative)
__device__ __forceinline__ void split2(float v, __bf16* h, __bf16* l) {
    __bf16 hh = (__bf16)v;
    *h = hh;
    *l = (__bf16)(v - (float)hh);
}

// ---------------- K1: forward D (real->17) + W DFT per (b,c,h) plane, via split-bf16 MFMA ----------------
// Stage D: A1[w][kd] = sum_d x[w][d] * e^{-2pi i kd d/32}   (2 real GEMMs, M=w N=kd K=d)
// Stage W: Z[kw][kd] = sum_w e^{-2pi i kw w/32} * A1[w][kd]  (complex GEMM, M=kw N=kd K=w)
__global__ __launch_bounds__(256) void k1_fwd_dw(const float* __restrict__ x,
                                                 float2* __restrict__ A) {
    __shared__ float2 tw[32];
    __shared__ __align__(16) __bf16 sXh[32][40], sXl[32][40];                                  // A-op [w][d]
    __shared__ __align__(16) __bf16 sErh[32][40], sErl[32][40], sEih[32][40], sEil[32][40];    // E[r][c]=e^{-2pi i rc/32} (symmetric)
    __shared__ __align__(16) __bf16 sArh[32][40], sArl[32][40], sAih[32][40], sAil[32][40];    // B^T [kd][w]
    const int t = threadIdx.x;
    if (t < 32) { float s, c; sincosf(-TWOPI_32 * (float)t, &s, &c); tw[t] = make_float2(c, s); }
    __syncthreads();
    const size_t pb = (size_t)blockIdx.x * 1024;
    for (int idx = t; idx < 1024; idx += 256) {
        int r = idx >> 5, c = idx & 31;
        float2 e = tw[(r * c) & 31];
        split2(e.x, &sErh[r][c], &sErl[r][c]);
        split2(e.y, &sEih[r][c], &sEil[r][c]);
        split2(x[pb + idx], &sXh[r][c], &sXl[r][c]);   // r=w, c=d
    }
    __syncthreads();
    const int wave = t >> 6, lane = t & 63, row = lane & 15, quad = lane >> 4;
    const int m0 = (wave >> 1) * 16, n0 = (wave & 1) * 16;
    // ---- D-stage: Ar = X*Er^T, Ai = X*Ei^T ----
    {
        bf16x8 xh  = ld8(&sXh[m0 + row][quad * 8]);
        bf16x8 xl  = ld8(&sXl[m0 + row][quad * 8]);
        bf16x8 erh = ld8(&sErh[n0 + row][quad * 8]);
        bf16x8 erl = ld8(&sErl[n0 + row][quad * 8]);
        bf16x8 eih = ld8(&sEih[n0 + row][quad * 8]);
        bf16x8 eil = ld8(&sEil[n0 + row][quad * 8]);
        f32x4 ar = {0.f,0.f,0.f,0.f}, ai = {0.f,0.f,0.f,0.f};
        ar = MFMA(xh, erh, ar, 0,0,0); ar = MFMA(xh, erl, ar, 0,0,0); ar = MFMA(xl, erh, ar, 0,0,0);
        ai = MFMA(xh, eih, ai, 0,0,0); ai = MFMA(xh, eil, ai, 0,0,0); ai = MFMA(xl, eih, ai, 0,0,0);
        #pragma unroll
        for (int r4 = 0; r4 < 4; r4++) {
            int w = m0 + quad * 4 + r4, kd = n0 + row;
            split2(ar[r4], &sArh[kd][w], &sArl[kd][w]);
            split2(ai[r4], &sAih[kd][w], &sAil[kd][w]);
        }
    }
    __syncthreads();
    // ---- W-stage: Z = E * A1 (complex) ----
    {
        bf16x8 erh = ld8(&sErh[m0 + row][quad * 8]);
        bf16x8 erl = ld8(&sErl[m0 + row][quad * 8]);
        bf16x8 eih = ld8(&sEih[m0 + row][quad * 8]);
        bf16x8 eil = ld8(&sEil[m0 + row][quad * 8]);
        bf16x8 arh = ld8(&sArh[n0 + row][quad * 8]);
        bf16x8 arl = ld8(&sArl[n0 + row][quad * 8]);
        bf16x8 aih = ld8(&sAih[n0 + row][quad * 8]);
        bf16x8 ail = ld8(&sAil[n0 + row][quad * 8]);
        f32x4 rp = {0.f,0.f,0.f,0.f}, rm = {0.f,0.f,0.f,0.f}, im = {0.f,0.f,0.f,0.f};
        rp = MFMA(erh, arh, rp, 0,0,0); rp = MFMA(erh, arl, rp, 0,0,0); rp = MFMA(erl, arh, rp, 0,0,0);
        rm = MFMA(eih, aih, rm, 0,0,0); rm = MFMA(eih, ail, rm, 0,0,0); rm = MFMA(eil, aih, rm, 0,0,0);
        im = MFMA(erh, aih, im, 0,0,0); im = MFMA(erh, ail, im, 0,0,0); im = MFMA(erl, aih, im, 0,0,0);
        im = MFMA(eih, arh, im, 0,0,0); im = MFMA(eih, arl, im, 0,0,0); im = MFMA(eil, arh, im, 0,0,0);
        const size_t ab = (size_t)blockIdx.x * PLANE;
        int kd = n0 + row;
        if (kd < DR) {
            #pragma unroll
            for (int r4 = 0; r4 < 4; r4++) {
                int kw = m0 + quad * 4 + r4;
                A[ab + kw * DR + kd] = make_float2((rp[r4] - rm[r4]) * ORTHO, im[r4] * ORTHO);
            }
        }
    }
}

// ---------------- K2: H-axis complex DFT via bf16 MFMA, in-place (unchanged) ----------------
template <bool INV>
__global__ __launch_bounds__(256) void k2_fft_h(float2* __restrict__ A) {
    __shared__ float2 twf[32];
    __shared__ __align__(16) __bf16 sEr[32][40],  sEi[32][40];   // A-operand [kh][h]
    __shared__ __align__(16) __bf16 sBr[272][40], sBi[272][40];  // B^T operand [p][h]
    const int t = threadIdx.x;
    if (t < 32) {
        float s, c; sincosf(-TWOPI_32 * (float)t, &s, &c);
        twf[t] = make_float2(c, INV ? -s : s);
    }
    __syncthreads();
    for (int idx = t; idx < 1024; idx += 256) {
        int kh = idx >> 5, h = idx & 31;
        float2 e = twf[(kh * h) & 31];
        sEr[kh][h] = (__bf16)e.x;
        sEi[kh][h] = (__bf16)e.y;
    }
    const int p0g = blockIdx.x * 272;
    const size_t cb = (size_t)blockIdx.y * CSTRIDE;
    for (int idx = t; idx < 8704; idx += 256) {
        int h = idx / 272, p = idx - h * 272;
        float2 v = A[cb + (size_t)h * PLANE + p0g + p];
        sBr[p][h] = (__bf16)v.x;
        sBi[p][h] = (__bf16)v.y;
    }
    __syncthreads();
    const int wave = t >> 6, lane = t & 63, row = lane & 15, quad = lane >> 4;
    for (int j = wave; j < 34; j += 4) {     // 2 M-tiles x 17 N-tiles
        int mt = j & 1, nt = j >> 1;
        int m0 = mt * 16, n0 = nt * 16;
        bf16x8 ar = ld8(&sEr[m0 + row][quad * 8]);
        bf16x8 ai = ld8(&sEi[m0 + row][quad * 8]);
        bf16x8 br = ld8(&sBr[n0 + row][quad * 8]);
        bf16x8 bi = ld8(&sBi[n0 + row][quad * 8]);
        f32x4 rp = {0.f,0.f,0.f,0.f}, rm = {0.f,0.f,0.f,0.f}, im = {0.f,0.f,0.f,0.f};
        rp = MFMA(ar, br, rp, 0, 0, 0);
        rm = MFMA(ai, bi, rm, 0, 0, 0);
        im = MFMA(ar, bi, im, 0, 0, 0);
        im = MFMA(ai, br, im, 0, 0, 0);
        int p = p0g + n0 + row;
        #pragma unroll
        for (int r = 0; r < 4; r++) {
            int kh = m0 + quad * 4 + r;
            A[cb + (size_t)kh * PLANE + p] = make_float2(rp[r] - rm[r], im[r]);
        }
    }
}

// ---------------- K3: block-diagonal complex MLP via bf16 MFMA, in-place (unchanged) ----------------
__global__ __launch_bounds__(256) void k3_mix(float2* __restrict__ A,
    const float* __restrict__ w1r, const float* __restrict__ w1i,
    const float* __restrict__ w2r, const float* __restrict__ w2i,
    const float* __restrict__ b1r, const float* __restrict__ b1i,
    const float* __restrict__ b2r, const float* __restrict__ b2i) {
    __shared__ __align__(16) __bf16 sWr[96][104], sWi[96][104];  // A-operand: [o][i] = W^T
    __shared__ __align__(16) __bf16 sXr[64][104], sXi[64][104];  // B^T operand: [p][i]
    const int t = threadIdx.x;
    const int chunk = blockIdx.x, bn = blockIdx.y;
    const int b = bn >> 3, n = bn & 7;
    const size_t base = (size_t)(b * CH + n * 96) * CSTRIDE + chunk * 64;

    const float* W1r = w1r + n * 9216;
    const float* W1i = w1i + n * 9216;
    for (int idx = t; idx < 9216; idx += 256) {
        int i = idx / 96, o = idx - i * 96;
        sWr[o][i] = (__bf16)W1r[idx];
        sWi[o][i] = (__bf16)W1i[idx];
    }
    for (int idx = t; idx < 6144; idx += 256) {
        int i = idx >> 6, p = idx & 63;
        float2 v = A[base + (size_t)i * CSTRIDE + p];
        sXr[p][i] = (__bf16)v.x;
        sXi[p][i] = (__bf16)v.y;
    }
    __syncthreads();

    const int wave = t >> 6, lane = t & 63, row = lane & 15, quad = lane >> 4;
    float h1s[6][8];

    #pragma unroll
    for (int q = 0; q < 6; q++) {
        int job = wave * 6 + q, mt = job >> 2, nt = job & 3;
        int m0 = mt * 16, p0 = nt * 16;
        f32x4 rp = {0.f,0.f,0.f,0.f}, rm = {0.f,0.f,0.f,0.f}, im = {0.f,0.f,0.f,0.f};
        #pragma unroll
        for (int ks = 0; ks < 3; ks++) {
            int k0 = ks * 32 + quad * 8;
            bf16x8 ar = ld8(&sWr[m0 + row][k0]);
            bf16x8 ai = ld8(&sWi[m0 + row][k0]);
            bf16x8 br = ld8(&sXr[p0 + row][k0]);
            bf16x8 bi = ld8(&sXi[p0 + row][k0]);
            rp = MFMA(ar, br, rp, 0, 0, 0);
            rm = MFMA(ai, bi, rm, 0, 0, 0);
            im = MFMA(ar, bi, im, 0, 0, 0);
            im = MFMA(ai, br, im, 0, 0, 0);
        }
        #pragma unroll
        for (int r = 0; r < 4; r++) {
            int o = m0 + quad * 4 + r;
            float hr = b1r[n * 96 + o] + rp[r] - rm[r];
            float hi = b1i[n * 96 + o] + im[r];
            h1s[q][r]     = gelu_f(hr);
            h1s[q][4 + r] = gelu_f(hi);
        }
    }
    __syncthreads();

    #pragma unroll
    for (int q = 0; q < 6; q++) {
        int job = wave * 6 + q, mt = job >> 2, nt = job & 3;
        int m0 = mt * 16, p0 = nt * 16;
        int p = p0 + row;
        #pragma unroll
        for (int r = 0; r < 4; r++) {
            int o = m0 + quad * 4 + r;
            sXr[p][o] = (__bf16)h1s[q][r];
            sXi[p][o] = (__bf16)h1s[q][4 + r];
        }
    }
    const float* W2r = w2r + n * 9216;
    const float* W2i = w2i + n * 9216;
    for (int idx = t; idx < 9216; idx += 256) {
        int i = idx / 96, o = idx - i * 96;
        sWr[o][i] = (__bf16)W2r[idx];
        sWi[o][i] = (__bf16)W2i[idx];
    }
    __syncthreads();

    #pragma unroll
    for (int q = 0; q < 6; q++) {
        int job = wave * 6 + q, mt = job >> 2, nt = job & 3;
        int m0 = mt * 16, p0 = nt * 16;
        f32x4 rp = {0.f,0.f,0.f,0.f}, rm = {0.f,0.f,0.f,0.f}, im = {0.f,0.f,0.f,0.f};
        #pragma unroll
        for (int ks = 0; ks < 3; ks++) {
            int k0 = ks * 32 + quad * 8;
            bf16x8 ar = ld8(&sWr[m0 + row][k0]);
            bf16x8 ai = ld8(&sWi[m0 + row][k0]);
            bf16x8 br = ld8(&sXr[p0 + row][k0]);
            bf16x8 bi = ld8(&sXi[p0 + row][k0]);
            rp = MFMA(ar, br, rp, 0, 0, 0);
            rm = MFMA(ai, bi, rm, 0, 0, 0);
            im = MFMA(ar, bi, im, 0, 0, 0);
            im = MFMA(ai, br, im, 0, 0, 0);
        }
        int p = p0 + row;
        #pragma unroll
        for (int r = 0; r < 4; r++) {
            int o = m0 + quad * 4 + r;
            float hr = sshrink(b2r[n * 96 + o] + rp[r] - rm[r]);
            float hi = sshrink(b2i[n * 96 + o] + im[r]);
            A[base + (size_t)o * CSTRIDE + p] = make_float2(hr, hi);
        }
    }
}

// ---------------- K5: inverse W DFT + inverse real D DFT + residual, via split-bf16 MFMA ----------------
// Stage 1: G[w][kd] = sum_kw e^{+2pi i w kw/32} * Z[kw][kd]          (complex GEMM)
// Stage 2: out[w][d] = sum_kd c_kd*(Gr cos - Gi sin)(kd d)           (2 real GEMMs, hermitian-folded)
__global__ __launch_bounds__(256) void k5_inv_wd(const float2* __restrict__ A,
                                                 const float* __restrict__ x,
                                                 float* __restrict__ out) {
    __shared__ float2 tw[32];
    __shared__ __align__(16) __bf16 sErh[32][40], sErl[32][40], sEih[32][40], sEil[32][40]; // E+[r][c] (symmetric)
    __shared__ __align__(16) __bf16 sZrh[32][40], sZrl[32][40], sZih[32][40], sZil[32][40]; // B^T [kd][kw]
    __shared__ __align__(16) __bf16 sGrh[32][40], sGrl[32][40], sGih[32][40], sGil[32][40]; // A-op [w][kd]
    __shared__ __align__(16) __bf16 sCrh[32][40], sCrl[32][40], sCih[32][40], sCil[32][40]; // B^T [d][kd]
    const int t = threadIdx.x;
    if (t < 32) { float s, c; sincosf(TWOPI_32 * (float)t, &s, &c); tw[t] = make_float2(c, s); }
    __syncthreads();
    for (int idx = t; idx < 1024; idx += 256) {
        int r = idx >> 5, c = idx & 31;
        float2 e = tw[(r * c) & 31];
        split2(e.x, &sErh[r][c], &sErl[r][c]);
        split2(e.y, &sEih[r][c], &sEil[r][c]);
        // C weights: row=d(r), col=kd(c); c_kd = 1 for kd in {0,16}, 2 for 1..15, 0 for >=17
        float cf = (c == 0 || c == 16) ? 1.f : (c < DR ? 2.f : 0.f);
        split2(cf * e.x,  &sCrh[r][c], &sCrl[r][c]);
        split2(-cf * e.y, &sCih[r][c], &sCil[r][c]);
    }
    const size_t ab = (size_t)blockIdx.x * PLANE;
    for (int idx = t; idx < PLANE; idx += 256) {
        int kw = idx / DR, kd = idx - kw * DR;
        float2 v = A[ab + idx];
        split2(v.x, &sZrh[kd][kw], &sZrl[kd][kw]);
        split2(v.y, &sZih[kd][kw], &sZil[kd][kw]);
    }
    for (int idx = t; idx < 480; idx += 256) {      // zero pad rows kd=17..31
        int kd = DR + (idx >> 5), kw = idx & 31;
        sZrh[kd][kw] = (__bf16)0.f; sZrl[kd][kw] = (__bf16)0.f;
        sZih[kd][kw] = (__bf16)0.f; sZil[kd][kw] = (__bf16)0.f;
    }
    __syncthreads();
    const int wave = t >> 6, lane = t & 63, row = lane & 15, quad = lane >> 4;
    const int m0 = (wave >> 1) * 16, n0 = (wave & 1) * 16;
    // ---- stage 1: complex W-inverse ----
    {
        bf16x8 erh = ld8(&sErh[m0 + row][quad * 8]);
        bf16x8 erl = ld8(&sErl[m0 + row][quad * 8]);
        bf16x8 eih = ld8(&sEih[m0 + row][quad * 8]);
        bf16x8 eil = ld8(&sEil[m0 + row][quad * 8]);
        bf16x8 zrh = ld8(&sZrh[n0 + row][quad * 8]);
        bf16x8 zrl = ld8(&sZrl[n0 + row][quad * 8]);
        bf16x8 zih = ld8(&sZih[n0 + row][quad * 8]);
        bf16x8 zil = ld8(&sZil[n0 + row][quad * 8]);
        f32x4 rp = {0.f,0.f,0.f,0.f}, rm = {0.f,0.f,0.f,0.f}, im = {0.f,0.f,0.f,0.f};
        rp = MFMA(erh, zrh, rp, 0,0,0); rp = MFMA(erh, zrl, rp, 0,0,0); rp = MFMA(erl, zrh, rp, 0,0,0);
        rm = MFMA(eih, zih, rm, 0,0,0); rm = MFMA(eih, zil, rm, 0,0,0); rm = MFMA(eil, zih, rm, 0,0,0);
        im = MFMA(erh, zih, im, 0,0,0); im = MFMA(erh, zil, im, 0,0,0); im = MFMA(erl, zih, im, 0,0,0);
        im = MFMA(eih, zrh, im, 0,0,0); im = MFMA(eih, zrl, im, 0,0,0); im = MFMA(eil, zrh, im, 0,0,0);
        #pragma unroll
        for (int r4 = 0; r4 < 4; r4++) {
            int w = m0 + quad * 4 + r4, kd = n0 + row;
            split2(rp[r4] - rm[r4], &sGrh[w][kd], &sGrl[w][kd]);
            split2(im[r4],          &sGih[w][kd], &sGil[w][kd]);
        }
    }
    __syncthreads();
    // ---- stage 2: real D-inverse + residual ----
    {
        bf16x8 grh = ld8(&sGrh[m0 + row][quad * 8]);
        bf16x8 grl = ld8(&sGrl[m0 + row][quad * 8]);
        bf16x8 gih = ld8(&sGih[m0 + row][quad * 8]);
        bf16x8 gil = ld8(&sGil[m0 + row][quad * 8]);
        bf16x8 crh = ld8(&sCrh[n0 + row][quad * 8]);
        bf16x8 crl = ld8(&sCrl[n0 + row][quad * 8]);
        bf16x8 cih = ld8(&sCih[n0 + row][quad * 8]);
        bf16x8 cil = ld8(&sCil[n0 + row][quad * 8]);
        f32x4 acc = {0.f,0.f,0.f,0.f};
        acc = MFMA(grh, crh, acc, 0,0,0); acc = MFMA(grh, crl, acc, 0,0,0); acc = MFMA(grl, crh, acc, 0,0,0);
        acc = MFMA(gih, cih, acc, 0,0,0); acc = MFMA(gih, cil, acc, 0,0,0); acc = MFMA(gil, cih, acc, 0,0,0);
        const size_t pb = (size_t)blockIdx.x * 1024;
        int d = n0 + row;
        #pragma unroll
        for (int r4 = 0; r4 < 4; r4++) {
            int w = m0 + quad * 4 + r4;
            out[pb + w * 32 + d] = acc[r4] * ORTHO + x[pb + w * 32 + d];
        }
    }
}

extern "C" void kernel_launch(void* const* d_in, const int* in_sizes, int n_in,
                              void* d_out, int out_size, void* d_ws, size_t ws_size,
                              hipStream_t stream) {
    const float* x   = (const float*)d_in[0];
    const float* w1r = (const float*)d_in[1];
    const float* w1i = (const float*)d_in[2];
    const float* w2r = (const float*)d_in[3];
    const float* w2i = (const float*)d_in[4];
    const float* b1r = (const float*)d_in[5];
    const float* b1i = (const float*)d_in[6];
    const float* b2r = (const float*)d_in[7];
    const float* b2i = (const float*)d_in[8];
    float* out = (float*)d_out;
    float2* A = (float2*)d_ws;   // 49152*544*8 = 214 MB spectrum buffer

    k1_fwd_dw<<<NVOL, 256, 0, stream>>>(x, A);
    k2_fft_h<false><<<dim3(2, 1536), 256, 0, stream>>>(A);
    k3_mix<<<dim3(272, 16), 256, 0, stream>>>(A, w1r, w1i, w2r, w2i, b1r, b1i, b2r, b2i);
    k2_fft_h<true><<<dim3(2, 1536), 256, 0, stream>>>(A);
    k5_inv_wd<<<NVOL, 256, 0, stream>>>(A, x, out);
}

// Round 2
// 893.215 us; speedup vs baseline: 1.4517x; 1.1080x over previous
//
#include <hip/hip_runtime.h>
#include <math.h>

// AFNO-3D: rfftn(32^3, ortho) -> blockdiag complex MLP (8 x 96x96, GELU, softshrink) -> irfftn + residual
// B=2, C=768 (8 blocks x 96), H=W=D=32, Dr=17. kept==Dr -> no truncation.
//
// Round 2: k1/k5 were latency/occupancy-bound (33% occ = 3 blocks/CU LDS cap; VALUBusy
// dominated by per-block twiddle regeneration). Twiddle/C tables now precomputed once
// (k0 -> __device__ globals), E/C/X operands loaded direct to regs, LDS reduced to the
// true inter-stage transpose buffers only (k1: 10 KB, k5: 10 KB aliased Z/G).

#define CH    768
#define DR    17
#define PLANE 544            // 32*17 (kw,kd) plane elements
#define NVOL  49152          // B*C*H = 2*768*32
#define CSTRIDE 17408        // 32*PLANE, per-channel complex elements
#define ORTHO 0.0055242717280199026f   // 1/sqrt(32768)
#define TWOPI_32 0.19634954084936207f  // 2*pi/32

typedef __bf16 bf16x8 __attribute__((ext_vector_type(8)));
typedef float  f32x4  __attribute__((ext_vector_type(4)));

#define MFMA __builtin_amdgcn_mfma_f32_16x16x32_bf16

__device__ __forceinline__ float gelu_f(float v) {
    return 0.5f * v * (1.0f + erff(v * 0.7071067811865475f));
}
__device__ __forceinline__ float sshrink(float v) {
    float a = fabsf(v) - 0.01f;
    return a > 0.f ? copysignf(a, v) : 0.f;
}
__device__ __forceinline__ bf16x8 ld8(const __bf16* p) { return *(const bf16x8*)p; }
// split v into bf16 hi + bf16 lo (~17 mantissa bits through a 3-product MFMA)
__device__ __forceinline__ void split2(float v, __bf16* h, __bf16* l) {
    __bf16 hh = (__bf16)v;
    *h = hh;
    *l = (__bf16)(v - (float)hh);
}

// Precomputed split-bf16 tables, identical for every block:
// gEf = e^{-2pi i rc/32}: [0]=cos_h [1]=cos_l [2]=sin_h [3]=sin_l (sin of NEGATIVE angle)
// gEb = e^{+2pi i rc/32}
// gC  = hermitian-folded inverse-D weights: cf*cos(+th), -cf*sin(+th), split
__device__ __align__(16) __bf16 gEf[4][1024];
__device__ __align__(16) __bf16 gEb[4][1024];
__device__ __align__(16) __bf16 gC [4][1024];

__global__ void k0_tables() {
    int idx = blockIdx.x * 256 + threadIdx.x;
    if (idx >= 1024) return;
    int c = idx & 31;
    int r = idx >> 5;
    float ang = TWOPI_32 * (float)((r * c) & 31);
    float s, co; sincosf(ang, &s, &co);
    __bf16 h, l;
    split2(co, &h, &l);  gEf[0][idx] = h; gEf[1][idx] = l;
                         gEb[0][idx] = h; gEb[1][idx] = l;
    split2(-s, &h, &l);  gEf[2][idx] = h; gEf[3][idx] = l;
    split2(s, &h, &l);   gEb[2][idx] = h; gEb[3][idx] = l;
    float cf = (c == 0 || c == 16) ? 1.f : (c < DR ? 2.f : 0.f);
    split2(cf * co, &h, &l); gC[0][idx] = h; gC[1][idx] = l;
    split2(-cf * s, &h, &l); gC[2][idx] = h; gC[3][idx] = l;
}

// ---------------- K1: forward D (real->17) + W DFT per (b,c,h) plane, split-bf16 MFMA ----------------
// Stage D: A1[w][kd] = sum_d x[w][d] e^{-2pi i kd d/32};  Stage W: Z[kw][kd] = sum_w e^{-2pi i kw w/32} A1[w][kd]
__global__ __launch_bounds__(256) void k1_fwd_dw(const float* __restrict__ x,
                                                 float2* __restrict__ A) {
    __shared__ __align__(16) __bf16 sArh[32][40], sArl[32][40], sAih[32][40], sAil[32][40]; // B^T [kd][w]
    const int t = threadIdx.x;
    const int wave = t >> 6, lane = t & 63, row = lane & 15, quad = lane >> 4;
    const int m0 = (wave >> 1) * 16, n0 = (wave & 1) * 16;
    const size_t pb = (size_t)blockIdx.x * 1024;

    // X fragment direct from global: rows m0+row (=w), cols quad*8..+8 (=d)
    const float* xp = x + pb + (size_t)(m0 + row) * 32 + quad * 8;
    f32x4 x0 = *(const f32x4*)xp;
    f32x4 x1 = *(const f32x4*)(xp + 4);
    bf16x8 xh, xl;
    #pragma unroll
    for (int j = 0; j < 4; j++) { __bf16 h = (__bf16)x0[j]; xh[j] = h; xl[j] = (__bf16)(x0[j] - (float)h); }
    #pragma unroll
    for (int j = 0; j < 4; j++) { __bf16 h = (__bf16)x1[j]; xh[4+j] = h; xl[4+j] = (__bf16)(x1[j] - (float)h); }

    // ---- D-stage ----
    {
        const int ed = (n0 + row) * 32 + quad * 8;   // E[kd][d]
        bf16x8 erh = *(const bf16x8*)&gEf[0][ed];
        bf16x8 erl = *(const bf16x8*)&gEf[1][ed];
        bf16x8 eih = *(const bf16x8*)&gEf[2][ed];
        bf16x8 eil = *(const bf16x8*)&gEf[3][ed];
        f32x4 ar = {0.f,0.f,0.f,0.f}, ai = {0.f,0.f,0.f,0.f};
        ar = MFMA(xh, erh, ar, 0,0,0); ar = MFMA(xh, erl, ar, 0,0,0); ar = MFMA(xl, erh, ar, 0,0,0);
        ai = MFMA(xh, eih, ai, 0,0,0); ai = MFMA(xh, eil, ai, 0,0,0); ai = MFMA(xl, eih, ai, 0,0,0);
        #pragma unroll
        for (int r4 = 0; r4 < 4; r4++) {
            int w = m0 + quad * 4 + r4, kd = n0 + row;
            split2(ar[r4], &sArh[kd][w], &sArl[kd][w]);
            split2(ai[r4], &sAih[kd][w], &sAil[kd][w]);
        }
    }
    __syncthreads();
    // ---- W-stage ----
    {
        const int ew = (m0 + row) * 32 + quad * 8;   // E[kw][w]
        bf16x8 frh = *(const bf16x8*)&gEf[0][ew];
        bf16x8 frl = *(const bf16x8*)&gEf[1][ew];
        bf16x8 fih = *(const bf16x8*)&gEf[2][ew];
        bf16x8 fil = *(const bf16x8*)&gEf[3][ew];
        bf16x8 arh = ld8(&sArh[n0 + row][quad * 8]);
        bf16x8 arl = ld8(&sArl[n0 + row][quad * 8]);
        bf16x8 aih = ld8(&sAih[n0 + row][quad * 8]);
        bf16x8 ail = ld8(&sAil[n0 + row][quad * 8]);
        f32x4 rp = {0.f,0.f,0.f,0.f}, rm = {0.f,0.f,0.f,0.f}, im = {0.f,0.f,0.f,0.f};
        rp = MFMA(frh, arh, rp, 0,0,0); rp = MFMA(frh, arl, rp, 0,0,0); rp = MFMA(frl, arh, rp, 0,0,0);
        rm = MFMA(fih, aih, rm, 0,0,0); rm = MFMA(fih, ail, rm, 0,0,0); rm = MFMA(fil, aih, rm, 0,0,0);
        im = MFMA(frh, aih, im, 0,0,0); im = MFMA(frh, ail, im, 0,0,0); im = MFMA(frl, aih, im, 0,0,0);
        im = MFMA(fih, arh, im, 0,0,0); im = MFMA(fih, arl, im, 0,0,0); im = MFMA(fil, arh, im, 0,0,0);
        const size_t ab = (size_t)blockIdx.x * PLANE;
        int kd = n0 + row;
        if (kd < DR) {
            #pragma unroll
            for (int r4 = 0; r4 < 4; r4++) {
                int kw = m0 + quad * 4 + r4;
                A[ab + kw * DR + kd] = make_float2((rp[r4] - rm[r4]) * ORTHO, im[r4] * ORTHO);
            }
        }
    }
}

// ---------------- K2: H-axis complex DFT via bf16 MFMA, in-place (unchanged) ----------------
template <bool INV>
__global__ __launch_bounds__(256) void k2_fft_h(float2* __restrict__ A) {
    __shared__ float2 twf[32];
    __shared__ __align__(16) __bf16 sEr[32][40],  sEi[32][40];   // A-operand [kh][h]
    __shared__ __align__(16) __bf16 sBr[272][40], sBi[272][40];  // B^T operand [p][h]
    const int t = threadIdx.x;
    if (t < 32) {
        float s, c; sincosf(-TWOPI_32 * (float)t, &s, &c);
        twf[t] = make_float2(c, INV ? -s : s);
    }
    __syncthreads();
    for (int idx = t; idx < 1024; idx += 256) {
        int kh = idx >> 5, h = idx & 31;
        float2 e = twf[(kh * h) & 31];
        sEr[kh][h] = (__bf16)e.x;
        sEi[kh][h] = (__bf16)e.y;
    }
    const int p0g = blockIdx.x * 272;
    const size_t cb = (size_t)blockIdx.y * CSTRIDE;
    for (int idx = t; idx < 8704; idx += 256) {
        int h = idx / 272, p = idx - h * 272;
        float2 v = A[cb + (size_t)h * PLANE + p0g + p];
        sBr[p][h] = (__bf16)v.x;
        sBi[p][h] = (__bf16)v.y;
    }
    __syncthreads();
    const int wave = t >> 6, lane = t & 63, row = lane & 15, quad = lane >> 4;
    for (int j = wave; j < 34; j += 4) {     // 2 M-tiles x 17 N-tiles
        int mt = j & 1, nt = j >> 1;
        int m0 = mt * 16, n0 = nt * 16;
        bf16x8 ar = ld8(&sEr[m0 + row][quad * 8]);
        bf16x8 ai = ld8(&sEi[m0 + row][quad * 8]);
        bf16x8 br = ld8(&sBr[n0 + row][quad * 8]);
        bf16x8 bi = ld8(&sBi[n0 + row][quad * 8]);
        f32x4 rp = {0.f,0.f,0.f,0.f}, rm = {0.f,0.f,0.f,0.f}, im = {0.f,0.f,0.f,0.f};
        rp = MFMA(ar, br, rp, 0, 0, 0);
        rm = MFMA(ai, bi, rm, 0, 0, 0);
        im = MFMA(ar, bi, im, 0, 0, 0);
        im = MFMA(ai, br, im, 0, 0, 0);
        int p = p0g + n0 + row;
        #pragma unroll
        for (int r = 0; r < 4; r++) {
            int kh = m0 + quad * 4 + r;
            A[cb + (size_t)kh * PLANE + p] = make_float2(rp[r] - rm[r], im[r]);
        }
    }
}

// ---------------- K3: block-diagonal complex MLP via bf16 MFMA, in-place (unchanged) ----------------
__global__ __launch_bounds__(256) void k3_mix(float2* __restrict__ A,
    const float* __restrict__ w1r, const float* __restrict__ w1i,
    const float* __restrict__ w2r, const float* __restrict__ w2i,
    const float* __restrict__ b1r, const float* __restrict__ b1i,
    const float* __restrict__ b2r, const float* __restrict__ b2i) {
    __shared__ __align__(16) __bf16 sWr[96][104], sWi[96][104];  // A-operand: [o][i] = W^T
    __shared__ __align__(16) __bf16 sXr[64][104], sXi[64][104];  // B^T operand: [p][i]
    const int t = threadIdx.x;
    const int chunk = blockIdx.x, bn = blockIdx.y;
    const int b = bn >> 3, n = bn & 7;
    const size_t base = (size_t)(b * CH + n * 96) * CSTRIDE + chunk * 64;

    const float* W1r = w1r + n * 9216;
    const float* W1i = w1i + n * 9216;
    for (int idx = t; idx < 9216; idx += 256) {
        int i = idx / 96, o = idx - i * 96;
        sWr[o][i] = (__bf16)W1r[idx];
        sWi[o][i] = (__bf16)W1i[idx];
    }
    for (int idx = t; idx < 6144; idx += 256) {
        int i = idx >> 6, p = idx & 63;
        float2 v = A[base + (size_t)i * CSTRIDE + p];
        sXr[p][i] = (__bf16)v.x;
        sXi[p][i] = (__bf16)v.y;
    }
    __syncthreads();

    const int wave = t >> 6, lane = t & 63, row = lane & 15, quad = lane >> 4;
    float h1s[6][8];

    #pragma unroll
    for (int q = 0; q < 6; q++) {
        int job = wave * 6 + q, mt = job >> 2, nt = job & 3;
        int m0 = mt * 16, p0 = nt * 16;
        f32x4 rp = {0.f,0.f,0.f,0.f}, rm = {0.f,0.f,0.f,0.f}, im = {0.f,0.f,0.f,0.f};
        #pragma unroll
        for (int ks = 0; ks < 3; ks++) {
            int k0 = ks * 32 + quad * 8;
            bf16x8 ar = ld8(&sWr[m0 + row][k0]);
            bf16x8 ai = ld8(&sWi[m0 + row][k0]);
            bf16x8 br = ld8(&sXr[p0 + row][k0]);
            bf16x8 bi = ld8(&sXi[p0 + row][k0]);
            rp = MFMA(ar, br, rp, 0, 0, 0);
            rm = MFMA(ai, bi, rm, 0, 0, 0);
            im = MFMA(ar, bi, im, 0, 0, 0);
            im = MFMA(ai, br, im, 0, 0, 0);
        }
        #pragma unroll
        for (int r = 0; r < 4; r++) {
            int o = m0 + quad * 4 + r;
            float hr = b1r[n * 96 + o] + rp[r] - rm[r];
            float hi = b1i[n * 96 + o] + im[r];
            h1s[q][r]     = gelu_f(hr);
            h1s[q][4 + r] = gelu_f(hi);
        }
    }
    __syncthreads();

    #pragma unroll
    for (int q = 0; q < 6; q++) {
        int job = wave * 6 + q, mt = job >> 2, nt = job & 3;
        int m0 = mt * 16, p0 = nt * 16;
        int p = p0 + row;
        #pragma unroll
        for (int r = 0; r < 4; r++) {
            int o = m0 + quad * 4 + r;
            sXr[p][o] = (__bf16)h1s[q][r];
            sXi[p][o] = (__bf16)h1s[q][4 + r];
        }
    }
    const float* W2r = w2r + n * 9216;
    const float* W2i = w2i + n * 9216;
    for (int idx = t; idx < 9216; idx += 256) {
        int i = idx / 96, o = idx - i * 96;
        sWr[o][i] = (__bf16)W2r[idx];
        sWi[o][i] = (__bf16)W2i[idx];
    }
    __syncthreads();

    #pragma unroll
    for (int q = 0; q < 6; q++) {
        int job = wave * 6 + q, mt = job >> 2, nt = job & 3;
        int m0 = mt * 16, p0 = nt * 16;
        f32x4 rp = {0.f,0.f,0.f,0.f}, rm = {0.f,0.f,0.f,0.f}, im = {0.f,0.f,0.f,0.f};
        #pragma unroll
        for (int ks = 0; ks < 3; ks++) {
            int k0 = ks * 32 + quad * 8;
            bf16x8 ar = ld8(&sWr[m0 + row][k0]);
            bf16x8 ai = ld8(&sWi[m0 + row][k0]);
            bf16x8 br = ld8(&sXr[p0 + row][k0]);
            bf16x8 bi = ld8(&sXi[p0 + row][k0]);
            rp = MFMA(ar, br, rp, 0, 0, 0);
            rm = MFMA(ai, bi, rm, 0, 0, 0);
            im = MFMA(ar, bi, im, 0, 0, 0);
            im = MFMA(ai, br, im, 0, 0, 0);
        }
        int p = p0 + row;
        #pragma unroll
        for (int r = 0; r < 4; r++) {
            int o = m0 + quad * 4 + r;
            float hr = sshrink(b2r[n * 96 + o] + rp[r] - rm[r]);
            float hi = sshrink(b2i[n * 96 + o] + im[r]);
            A[base + (size_t)o * CSTRIDE + p] = make_float2(hr, hi);
        }
    }
}

// ---------------- K5: inverse W DFT + inverse real D DFT + residual, split-bf16 MFMA ----------------
// Stage 1: G[w][kd] = sum_kw e^{+2pi i w kw/32} Z[kw][kd];  Stage 2: out[w][d] = sum_kd C[d][kd]·G (folded)
__global__ __launch_bounds__(256) void k5_inv_wd(const float2* __restrict__ A,
                                                 const float* __restrict__ x,
                                                 float* __restrict__ out) {
    // Z (stage-1 B^T [kd][kw]) and G (stage-2 A [w][kd]) alias the same buffers.
    __shared__ __align__(16) __bf16 sZrh[32][40], sZrl[32][40], sZih[32][40], sZil[32][40];
    const int t = threadIdx.x;
    const int wave = t >> 6, lane = t & 63, row = lane & 15, quad = lane >> 4;
    const int m0 = (wave >> 1) * 16, n0 = (wave & 1) * 16;
    const size_t ab = (size_t)blockIdx.x * PLANE;
    const size_t pb = (size_t)blockIdx.x * 1024;
    const int d = n0 + row;

    // residual loads issued early, consumed in the epilogue
    float xres[4];
    #pragma unroll
    for (int r4 = 0; r4 < 4; r4++)
        xres[r4] = x[pb + (size_t)(m0 + quad * 4 + r4) * 32 + d];

    // fill Z^T [kd][kw] (coalesced global read), zero-pad kd=17..31
    for (int idx = t; idx < PLANE; idx += 256) {
        int kw = idx / DR, kd = idx - kw * DR;
        float2 v = A[ab + idx];
        split2(v.x, &sZrh[kd][kw], &sZrl[kd][kw]);
        split2(v.y, &sZih[kd][kw], &sZil[kd][kw]);
    }
    for (int idx = t; idx < 480; idx += 256) {
        int kd = DR + (idx >> 5), kw = idx & 31;
        sZrh[kd][kw] = (__bf16)0.f; sZrl[kd][kw] = (__bf16)0.f;
        sZih[kd][kw] = (__bf16)0.f; sZil[kd][kw] = (__bf16)0.f;
    }
    __syncthreads();

    // ---- stage 1: complex W-inverse ----
    const int e1 = (m0 + row) * 32 + quad * 8;       // E+[w][kw]
    bf16x8 erh = *(const bf16x8*)&gEb[0][e1];
    bf16x8 erl = *(const bf16x8*)&gEb[1][e1];
    bf16x8 eih = *(const bf16x8*)&gEb[2][e1];
    bf16x8 eil = *(const bf16x8*)&gEb[3][e1];
    bf16x8 zrh = ld8(&sZrh[n0 + row][quad * 8]);
    bf16x8 zrl = ld8(&sZrl[n0 + row][quad * 8]);
    bf16x8 zih = ld8(&sZih[n0 + row][quad * 8]);
    bf16x8 zil = ld8(&sZil[n0 + row][quad * 8]);
    f32x4 rp = {0.f,0.f,0.f,0.f}, rm = {0.f,0.f,0.f,0.f}, im = {0.f,0.f,0.f,0.f};
    rp = MFMA(erh, zrh, rp, 0,0,0); rp = MFMA(erh, zrl, rp, 0,0,0); rp = MFMA(erl, zrh, rp, 0,0,0);
    rm = MFMA(eih, zih, rm, 0,0,0); rm = MFMA(eih, zil, rm, 0,0,0); rm = MFMA(eil, zih, rm, 0,0,0);
    im = MFMA(erh, zih, im, 0,0,0); im = MFMA(erh, zil, im, 0,0,0); im = MFMA(erl, zih, im, 0,0,0);
    im = MFMA(eih, zrh, im, 0,0,0); im = MFMA(eih, zrl, im, 0,0,0); im = MFMA(eil, zrh, im, 0,0,0);
    __syncthreads();   // all Z reads complete block-wide before overwrite as G
    #pragma unroll
    for (int r4 = 0; r4 < 4; r4++) {
        int w = m0 + quad * 4 + r4, kd = n0 + row;
        split2(rp[r4] - rm[r4], &sZrh[w][kd], &sZrl[w][kd]);   // now holds G[w][kd]
        split2(im[r4],          &sZih[w][kd], &sZil[w][kd]);
    }
    __syncthreads();

    // ---- stage 2: real D-inverse + residual ----
    const int c2 = d * 32 + quad * 8;                // C[d][kd]
    bf16x8 crh = *(const bf16x8*)&gC[0][c2];
    bf16x8 crl = *(const bf16x8*)&gC[1][c2];
    bf16x8 cih = *(const bf16x8*)&gC[2][c2];
    bf16x8 cil = *(const bf16x8*)&gC[3][c2];
    bf16x8 grh = ld8(&sZrh[m0 + row][quad * 8]);
    bf16x8 grl = ld8(&sZrl[m0 + row][quad * 8]);
    bf16x8 gih = ld8(&sZih[m0 + row][quad * 8]);
    bf16x8 gil = ld8(&sZil[m0 + row][quad * 8]);
    f32x4 acc = {0.f,0.f,0.f,0.f};
    acc = MFMA(grh, crh, acc, 0,0,0); acc = MFMA(grh, crl, acc, 0,0,0); acc = MFMA(grl, crh, acc, 0,0,0);
    acc = MFMA(gih, cih, acc, 0,0,0); acc = MFMA(gih, cil, acc, 0,0,0); acc = MFMA(gil, cih, acc, 0,0,0);
    #pragma unroll
    for (int r4 = 0; r4 < 4; r4++) {
        int w = m0 + quad * 4 + r4;
        out[pb + (size_t)w * 32 + d] = acc[r4] * ORTHO + xres[r4];
    }
}

extern "C" void kernel_launch(void* const* d_in, const int* in_sizes, int n_in,
                              void* d_out, int out_size, void* d_ws, size_t ws_size,
                              hipStream_t stream) {
    const float* x   = (const float*)d_in[0];
    const float* w1r = (const float*)d_in[1];
    const float* w1i = (const float*)d_in[2];
    const float* w2r = (const float*)d_in[3];
    const float* w2i = (const float*)d_in[4];
    const float* b1r = (const float*)d_in[5];
    const float* b1i = (const float*)d_in[6];
    const float* b2r = (const float*)d_in[7];
    const float* b2i = (const float*)d_in[8];
    float* out = (float*)d_out;
    float2* A = (float2*)d_ws;   // 49152*544*8 = 214 MB spectrum buffer

    k0_tables<<<4, 256, 0, stream>>>();
    k1_fwd_dw<<<NVOL, 256, 0, stream>>>(x, A);
    k2_fft_h<false><<<dim3(2, 1536), 256, 0, stream>>>(A);
    k3_mix<<<dim3(272, 16), 256, 0, stream>>>(A, w1r, w1i, w2r, w2i, b1r, b1i, b2r, b2i);
    k2_fft_h<true><<<dim3(2, 1536), 256, 0, stream>>>(A);
    k5_inv_wd<<<NVOL, 256, 0, stream>>>(A, x, out);
}

// Round 3
// 873.263 us; speedup vs baseline: 1.4848x; 1.0228x over previous
//
#include <hip/hip_runtime.h>
#include <math.h>

// AFNO-3D: rfftn(32^3, ortho) -> blockdiag complex MLP (8 x 96x96, GELU, softshrink) -> irfftn + residual
// B=2, C=768 (8 blocks x 96), H=W=D=32, Dr=17. kept==Dr -> no truncation.
//
// Round 3: k3 was re-staging 144 KB of fp32 weights through LDS per block (4352 blocks,
// identical weights) -> 8-way-conflicted transposed writes + cvt dominated (VALUBusy 38%,
// occ 21.6% from 66.5 KB LDS). Weights now converted/transposed ONCE (k0w -> 576 KB
// __device__ bf16 tables); k3 loads W fragments direct from L2. k2 likewise loads its
// E fragments from the precomputed twiddle tables (no per-block sincos/staging).

#define CH    768
#define DR    17
#define PLANE 544            // 32*17 (kw,kd) plane elements
#define NVOL  49152          // B*C*H = 2*768*32
#define CSTRIDE 17408        // 32*PLANE, per-channel complex elements
#define ORTHO 0.0055242717280199026f   // 1/sqrt(32768)
#define TWOPI_32 0.19634954084936207f  // 2*pi/32

typedef __bf16 bf16x8 __attribute__((ext_vector_type(8)));
typedef float  f32x4  __attribute__((ext_vector_type(4)));

#define MFMA __builtin_amdgcn_mfma_f32_16x16x32_bf16

__device__ __forceinline__ float gelu_f(float v) {
    return 0.5f * v * (1.0f + erff(v * 0.7071067811865475f));
}
__device__ __forceinline__ float sshrink(float v) {
    float a = fabsf(v) - 0.01f;
    return a > 0.f ? copysignf(a, v) : 0.f;
}
__device__ __forceinline__ bf16x8 ld8(const __bf16* p) { return *(const bf16x8*)p; }
// split v into bf16 hi + bf16 lo (~17 mantissa bits through a 3-product MFMA)
__device__ __forceinline__ void split2(float v, __bf16* h, __bf16* l) {
    __bf16 hh = (__bf16)v;
    *h = hh;
    *l = (__bf16)(v - (float)hh);
}

// Precomputed split-bf16 twiddle tables (identical for every block):
// gEf = e^{-2pi i rc/32}: [0]=cos_h [1]=cos_l [2]=sin_h [3]=sin_l (imag of e^{-i})
// gEb = e^{+2pi i rc/32}
// gC  = hermitian-folded inverse-D weights: cf*cos, -cf*sin, split
__device__ __align__(16) __bf16 gEf[4][1024];
__device__ __align__(16) __bf16 gEb[4][1024];
__device__ __align__(16) __bf16 gC [4][1024];

__global__ void k0_tables() {
    int idx = blockIdx.x * 256 + threadIdx.x;
    if (idx >= 1024) return;
    int c = idx & 31;
    int r = idx >> 5;
    float ang = TWOPI_32 * (float)((r * c) & 31);
    float s, co; sincosf(ang, &s, &co);
    __bf16 h, l;
    split2(co, &h, &l);  gEf[0][idx] = h; gEf[1][idx] = l;
                         gEb[0][idx] = h; gEb[1][idx] = l;
    split2(-s, &h, &l);  gEf[2][idx] = h; gEf[3][idx] = l;
    split2(s, &h, &l);   gEb[2][idx] = h; gEb[3][idx] = l;
    float cf = (c == 0 || c == 16) ? 1.f : (c < DR ? 2.f : 0.f);
    split2(cf * co, &h, &l); gC[0][idx] = h; gC[1][idx] = l;
    split2(-cf * s, &h, &l); gC[2][idx] = h; gC[3][idx] = l;
}

// Precomputed bf16 transposed weights: [n][o][i], row stride 96 els = 192 B (16B-aligned)
__device__ __align__(16) __bf16 gW1r[73728], gW1i[73728], gW2r[73728], gW2i[73728];

__global__ void k0w(const float* __restrict__ w1r, const float* __restrict__ w1i,
                    const float* __restrict__ w2r, const float* __restrict__ w2i) {
    int idx = blockIdx.x * 256 + threadIdx.x;      // idx = (n*96 + o)*96 + i  (write-coalesced)
    if (idx >= 73728) return;
    int i = idx % 96, no = idx / 96;
    int o = no % 96, n = no / 96;
    int src = n * 9216 + i * 96 + o;
    gW1r[idx] = (__bf16)w1r[src];
    gW1i[idx] = (__bf16)w1i[src];
    gW2r[idx] = (__bf16)w2r[src];
    gW2i[idx] = (__bf16)w2i[src];
}

// ---------------- K1: forward D (real->17) + W DFT per (b,c,h) plane, split-bf16 MFMA ----------------
__global__ __launch_bounds__(256) void k1_fwd_dw(const float* __restrict__ x,
                                                 float2* __restrict__ A) {
    __shared__ __align__(16) __bf16 sArh[32][40], sArl[32][40], sAih[32][40], sAil[32][40]; // B^T [kd][w]
    const int t = threadIdx.x;
    const int wave = t >> 6, lane = t & 63, row = lane & 15, quad = lane >> 4;
    const int m0 = (wave >> 1) * 16, n0 = (wave & 1) * 16;
    const size_t pb = (size_t)blockIdx.x * 1024;

    const float* xp = x + pb + (size_t)(m0 + row) * 32 + quad * 8;
    f32x4 x0 = *(const f32x4*)xp;
    f32x4 x1 = *(const f32x4*)(xp + 4);
    bf16x8 xh, xl;
    #pragma unroll
    for (int j = 0; j < 4; j++) { __bf16 h = (__bf16)x0[j]; xh[j] = h; xl[j] = (__bf16)(x0[j] - (float)h); }
    #pragma unroll
    for (int j = 0; j < 4; j++) { __bf16 h = (__bf16)x1[j]; xh[4+j] = h; xl[4+j] = (__bf16)(x1[j] - (float)h); }

    // ---- D-stage ----
    {
        const int ed = (n0 + row) * 32 + quad * 8;   // E[kd][d]
        bf16x8 erh = *(const bf16x8*)&gEf[0][ed];
        bf16x8 erl = *(const bf16x8*)&gEf[1][ed];
        bf16x8 eih = *(const bf16x8*)&gEf[2][ed];
        bf16x8 eil = *(const bf16x8*)&gEf[3][ed];
        f32x4 ar = {0.f,0.f,0.f,0.f}, ai = {0.f,0.f,0.f,0.f};
        ar = MFMA(xh, erh, ar, 0,0,0); ar = MFMA(xh, erl, ar, 0,0,0); ar = MFMA(xl, erh, ar, 0,0,0);
        ai = MFMA(xh, eih, ai, 0,0,0); ai = MFMA(xh, eil, ai, 0,0,0); ai = MFMA(xl, eih, ai, 0,0,0);
        #pragma unroll
        for (int r4 = 0; r4 < 4; r4++) {
            int w = m0 + quad * 4 + r4, kd = n0 + row;
            split2(ar[r4], &sArh[kd][w], &sArl[kd][w]);
            split2(ai[r4], &sAih[kd][w], &sAil[kd][w]);
        }
    }
    __syncthreads();
    // ---- W-stage ----
    {
        const int ew = (m0 + row) * 32 + quad * 8;   // E[kw][w]
        bf16x8 frh = *(const bf16x8*)&gEf[0][ew];
        bf16x8 frl = *(const bf16x8*)&gEf[1][ew];
        bf16x8 fih = *(const bf16x8*)&gEf[2][ew];
        bf16x8 fil = *(const bf16x8*)&gEf[3][ew];
        bf16x8 arh = ld8(&sArh[n0 + row][quad * 8]);
        bf16x8 arl = ld8(&sArl[n0 + row][quad * 8]);
        bf16x8 aih = ld8(&sAih[n0 + row][quad * 8]);
        bf16x8 ail = ld8(&sAil[n0 + row][quad * 8]);
        f32x4 rp = {0.f,0.f,0.f,0.f}, rm = {0.f,0.f,0.f,0.f}, im = {0.f,0.f,0.f,0.f};
        rp = MFMA(frh, arh, rp, 0,0,0); rp = MFMA(frh, arl, rp, 0,0,0); rp = MFMA(frl, arh, rp, 0,0,0);
        rm = MFMA(fih, aih, rm, 0,0,0); rm = MFMA(fih, ail, rm, 0,0,0); rm = MFMA(fil, aih, rm, 0,0,0);
        im = MFMA(frh, aih, im, 0,0,0); im = MFMA(frh, ail, im, 0,0,0); im = MFMA(frl, aih, im, 0,0,0);
        im = MFMA(fih, arh, im, 0,0,0); im = MFMA(fih, arl, im, 0,0,0); im = MFMA(fil, arh, im, 0,0,0);
        const size_t ab = (size_t)blockIdx.x * PLANE;
        int kd = n0 + row;
        if (kd < DR) {
            #pragma unroll
            for (int r4 = 0; r4 < 4; r4++) {
                int kw = m0 + quad * 4 + r4;
                A[ab + kw * DR + kd] = make_float2((rp[r4] - rm[r4]) * ORTHO, im[r4] * ORTHO);
            }
        }
    }
}

// ---------------- K2: H-axis complex DFT via bf16 MFMA, in-place ----------------
// E fragments direct from precomputed tables (bit-identical to prior per-block sincos).
template <bool INV>
__global__ __launch_bounds__(256) void k2_fft_h(float2* __restrict__ A) {
    __shared__ __align__(16) __bf16 sBr[272][40], sBi[272][40];  // B^T operand [p][h]
    const int t = threadIdx.x;
    const int p0g = blockIdx.x * 272;
    const size_t cb = (size_t)blockIdx.y * CSTRIDE;
    for (int idx = t; idx < 8704; idx += 256) {
        int h = idx / 272, p = idx - h * 272;
        float2 v = A[cb + (size_t)h * PLANE + p0g + p];
        sBr[p][h] = (__bf16)v.x;
        sBi[p][h] = (__bf16)v.y;
    }
    __syncthreads();
    const int wave = t >> 6, lane = t & 63, row = lane & 15, quad = lane >> 4;
    const __bf16* Er = gEf[0];
    const __bf16* Ei = INV ? gEb[2] : gEf[2];
    // E[kh][h]: kh = mt*16+row, h = quad*8..+8 — only 2 mt values, hoisted
    bf16x8 er0 = *(const bf16x8*)&Er[row * 32 + quad * 8];
    bf16x8 ei0 = *(const bf16x8*)&Ei[row * 32 + quad * 8];
    bf16x8 er1 = *(const bf16x8*)&Er[(16 + row) * 32 + quad * 8];
    bf16x8 ei1 = *(const bf16x8*)&Ei[(16 + row) * 32 + quad * 8];
    for (int j = wave; j < 34; j += 4) {     // 2 M-tiles x 17 N-tiles
        int mt = j & 1, nt = j >> 1;
        int m0 = mt * 16, n0 = nt * 16;
        bf16x8 ar = mt ? er1 : er0;
        bf16x8 ai = mt ? ei1 : ei0;
        bf16x8 br = ld8(&sBr[n0 + row][quad * 8]);
        bf16x8 bi = ld8(&sBi[n0 + row][quad * 8]);
        f32x4 rp = {0.f,0.f,0.f,0.f}, rm = {0.f,0.f,0.f,0.f}, im = {0.f,0.f,0.f,0.f};
        rp = MFMA(ar, br, rp, 0, 0, 0);
        rm = MFMA(ai, bi, rm, 0, 0, 0);
        im = MFMA(ar, bi, im, 0, 0, 0);
        im = MFMA(ai, br, im, 0, 0, 0);
        int p = p0g + n0 + row;
        #pragma unroll
        for (int r = 0; r < 4; r++) {
            int kh = m0 + quad * 4 + r;
            A[cb + (size_t)kh * PLANE + p] = make_float2(rp[r] - rm[r], im[r]);
        }
    }
}

// ---------------- K3: block-diagonal complex MLP via bf16 MFMA, in-place ----------------
// W fragments direct from precomputed gW tables (L2-resident); LDS only for X/h1 transpose.
__global__ __launch_bounds__(256) void k3_mix(float2* __restrict__ A,
    const float* __restrict__ b1r, const float* __restrict__ b1i,
    const float* __restrict__ b2r, const float* __restrict__ b2i) {
    __shared__ __align__(16) __bf16 sXr[64][104], sXi[64][104];  // B^T operand: [p][i]
    const int t = threadIdx.x;
    const int chunk = blockIdx.x, bn = blockIdx.y;
    const int b = bn >> 3, n = bn & 7;
    const size_t base = (size_t)(b * CH + n * 96) * CSTRIDE + chunk * 64;

    for (int idx = t; idx < 6144; idx += 256) {
        int i = idx >> 6, p = idx & 63;
        float2 v = A[base + (size_t)i * CSTRIDE + p];
        sXr[p][i] = (__bf16)v.x;
        sXi[p][i] = (__bf16)v.y;
    }
    __syncthreads();

    const int wave = t >> 6, lane = t & 63, row = lane & 15, quad = lane >> 4;
    const __bf16* W1r = &gW1r[n * 9216];
    const __bf16* W1i = &gW1i[n * 9216];
    const __bf16* W2r = &gW2r[n * 9216];
    const __bf16* W2i = &gW2i[n * 9216];
    float h1s[6][8];

    #pragma unroll
    for (int q = 0; q < 6; q++) {
        int job = wave * 6 + q, mt = job >> 2, nt = job & 3;
        int m0 = mt * 16, p0 = nt * 16;
        f32x4 rp = {0.f,0.f,0.f,0.f}, rm = {0.f,0.f,0.f,0.f}, im = {0.f,0.f,0.f,0.f};
        #pragma unroll
        for (int ks = 0; ks < 3; ks++) {
            int k0 = ks * 32 + quad * 8;
            bf16x8 ar = ld8(&W1r[(m0 + row) * 96 + k0]);
            bf16x8 ai = ld8(&W1i[(m0 + row) * 96 + k0]);
            bf16x8 br = ld8(&sXr[p0 + row][k0]);
            bf16x8 bi = ld8(&sXi[p0 + row][k0]);
            rp = MFMA(ar, br, rp, 0, 0, 0);
            rm = MFMA(ai, bi, rm, 0, 0, 0);
            im = MFMA(ar, bi, im, 0, 0, 0);
            im = MFMA(ai, br, im, 0, 0, 0);
        }
        #pragma unroll
        for (int r = 0; r < 4; r++) {
            int o = m0 + quad * 4 + r;
            float hr = b1r[n * 96 + o] + rp[r] - rm[r];
            float hi = b1i[n * 96 + o] + im[r];
            h1s[q][r]     = gelu_f(hr);
            h1s[q][4 + r] = gelu_f(hi);
        }
    }
    __syncthreads();   // all waves done reading sX

    #pragma unroll
    for (int q = 0; q < 6; q++) {
        int job = wave * 6 + q, mt = job >> 2, nt = job & 3;
        int m0 = mt * 16, p0 = nt * 16;
        int p = p0 + row;
        #pragma unroll
        for (int r = 0; r < 4; r++) {
            int o = m0 + quad * 4 + r;
            sXr[p][o] = (__bf16)h1s[q][r];
            sXi[p][o] = (__bf16)h1s[q][4 + r];
        }
    }
    __syncthreads();

    #pragma unroll
    for (int q = 0; q < 6; q++) {
        int job = wave * 6 + q, mt = job >> 2, nt = job & 3;
        int m0 = mt * 16, p0 = nt * 16;
        f32x4 rp = {0.f,0.f,0.f,0.f}, rm = {0.f,0.f,0.f,0.f}, im = {0.f,0.f,0.f,0.f};
        #pragma unroll
        for (int ks = 0; ks < 3; ks++) {
            int k0 = ks * 32 + quad * 8;
            bf16x8 ar = ld8(&W2r[(m0 + row) * 96 + k0]);
            bf16x8 ai = ld8(&W2i[(m0 + row) * 96 + k0]);
            bf16x8 br = ld8(&sXr[p0 + row][k0]);
            bf16x8 bi = ld8(&sXi[p0 + row][k0]);
            rp = MFMA(ar, br, rp, 0, 0, 0);
            rm = MFMA(ai, bi, rm, 0, 0, 0);
            im = MFMA(ar, bi, im, 0, 0, 0);
            im = MFMA(ai, br, im, 0, 0, 0);
        }
        int p = p0 + row;
        #pragma unroll
        for (int r = 0; r < 4; r++) {
            int o = m0 + quad * 4 + r;
            float hr = sshrink(b2r[n * 96 + o] + rp[r] - rm[r]);
            float hi = sshrink(b2i[n * 96 + o] + im[r]);
            A[base + (size_t)o * CSTRIDE + p] = make_float2(hr, hi);
        }
    }
}

// ---------------- K5: inverse W DFT + inverse real D DFT + residual, split-bf16 MFMA ----------------
__global__ __launch_bounds__(256) void k5_inv_wd(const float2* __restrict__ A,
                                                 const float* __restrict__ x,
                                                 float* __restrict__ out) {
    // Z (stage-1 B^T [kd][kw]) and G (stage-2 A [w][kd]) alias the same buffers.
    __shared__ __align__(16) __bf16 sZrh[32][40], sZrl[32][40], sZih[32][40], sZil[32][40];
    const int t = threadIdx.x;
    const int wave = t >> 6, lane = t & 63, row = lane & 15, quad = lane >> 4;
    const int m0 = (wave >> 1) * 16, n0 = (wave & 1) * 16;
    const size_t ab = (size_t)blockIdx.x * PLANE;
    const size_t pb = (size_t)blockIdx.x * 1024;
    const int d = n0 + row;

    float xres[4];
    #pragma unroll
    for (int r4 = 0; r4 < 4; r4++)
        xres[r4] = x[pb + (size_t)(m0 + quad * 4 + r4) * 32 + d];

    for (int idx = t; idx < PLANE; idx += 256) {
        int kw = idx / DR, kd = idx - kw * DR;
        float2 v = A[ab + idx];
        split2(v.x, &sZrh[kd][kw], &sZrl[kd][kw]);
        split2(v.y, &sZih[kd][kw], &sZil[kd][kw]);
    }
    for (int idx = t; idx < 480; idx += 256) {
        int kd = DR + (idx >> 5), kw = idx & 31;
        sZrh[kd][kw] = (__bf16)0.f; sZrl[kd][kw] = (__bf16)0.f;
        sZih[kd][kw] = (__bf16)0.f; sZil[kd][kw] = (__bf16)0.f;
    }
    __syncthreads();

    // ---- stage 1: complex W-inverse ----
    const int e1 = (m0 + row) * 32 + quad * 8;       // E+[w][kw]
    bf16x8 erh = *(const bf16x8*)&gEb[0][e1];
    bf16x8 erl = *(const bf16x8*)&gEb[1][e1];
    bf16x8 eih = *(const bf16x8*)&gEb[2][e1];
    bf16x8 eil = *(const bf16x8*)&gEb[3][e1];
    bf16x8 zrh = ld8(&sZrh[n0 + row][quad * 8]);
    bf16x8 zrl = ld8(&sZrl[n0 + row][quad * 8]);
    bf16x8 zih = ld8(&sZih[n0 + row][quad * 8]);
    bf16x8 zil = ld8(&sZil[n0 + row][quad * 8]);
    f32x4 rp = {0.f,0.f,0.f,0.f}, rm = {0.f,0.f,0.f,0.f}, im = {0.f,0.f,0.f,0.f};
    rp = MFMA(erh, zrh, rp, 0,0,0); rp = MFMA(erh, zrl, rp, 0,0,0); rp = MFMA(erl, zrh, rp, 0,0,0);
    rm = MFMA(eih, zih, rm, 0,0,0); rm = MFMA(eih, zil, rm, 0,0,0); rm = MFMA(eil, zih, rm, 0,0,0);
    im = MFMA(erh, zih, im, 0,0,0); im = MFMA(erh, zil, im, 0,0,0); im = MFMA(erl, zih, im, 0,0,0);
    im = MFMA(eih, zrh, im, 0,0,0); im = MFMA(eih, zrl, im, 0,0,0); im = MFMA(eil, zrh, im, 0,0,0);
    __syncthreads();   // all Z reads complete block-wide before overwrite as G
    #pragma unroll
    for (int r4 = 0; r4 < 4; r4++) {
        int w = m0 + quad * 4 + r4, kd = n0 + row;
        split2(rp[r4] - rm[r4], &sZrh[w][kd], &sZrl[w][kd]);   // now holds G[w][kd]
        split2(im[r4],          &sZih[w][kd], &sZil[w][kd]);
    }
    __syncthreads();

    // ---- stage 2: real D-inverse + residual ----
    const int c2 = d * 32 + quad * 8;                // C[d][kd]
    bf16x8 crh = *(const bf16x8*)&gC[0][c2];
    bf16x8 crl = *(const bf16x8*)&gC[1][c2];
    bf16x8 cih = *(const bf16x8*)&gC[2][c2];
    bf16x8 cil = *(const bf16x8*)&gC[3][c2];
    bf16x8 grh = ld8(&sZrh[m0 + row][quad * 8]);
    bf16x8 grl = ld8(&sZrl[m0 + row][quad * 8]);
    bf16x8 gih = ld8(&sZih[m0 + row][quad * 8]);
    bf16x8 gil = ld8(&sZil[m0 + row][quad * 8]);
    f32x4 acc = {0.f,0.f,0.f,0.f};
    acc = MFMA(grh, crh, acc, 0,0,0); acc = MFMA(grh, crl, acc, 0,0,0); acc = MFMA(grl, crh, acc, 0,0,0);
    acc = MFMA(gih, cih, acc, 0,0,0); acc = MFMA(gih, cil, acc, 0,0,0); acc = MFMA(gil, cih, acc, 0,0,0);
    #pragma unroll
    for (int r4 = 0; r4 < 4; r4++) {
        int w = m0 + quad * 4 + r4;
        out[pb + (size_t)w * 32 + d] = acc[r4] * ORTHO + xres[r4];
    }
}

extern "C" void kernel_launch(void* const* d_in, const int* in_sizes, int n_in,
                              void* d_out, int out_size, void* d_ws, size_t ws_size,
                              hipStream_t stream) {
    const float* x   = (const float*)d_in[0];
    const float* w1r = (const float*)d_in[1];
    const float* w1i = (const float*)d_in[2];
    const float* w2r = (const float*)d_in[3];
    const float* w2i = (const float*)d_in[4];
    const float* b1r = (const float*)d_in[5];
    const float* b1i = (const float*)d_in[6];
    const float* b2r = (const float*)d_in[7];
    const float* b2i = (const float*)d_in[8];
    float* out = (float*)d_out;
    float2* A = (float2*)d_ws;   // 49152*544*8 = 214 MB spectrum buffer

    k0_tables<<<4, 256, 0, stream>>>();
    k0w<<<288, 256, 0, stream>>>(w1r, w1i, w2r, w2i);
    k1_fwd_dw<<<NVOL, 256, 0, stream>>>(x, A);
    k2_fft_h<false><<<dim3(2, 1536), 256, 0, stream>>>(A);
    k3_mix<<<dim3(272, 16), 256, 0, stream>>>(A, b1r, b1i, b2r, b2i);
    k2_fft_h<true><<<dim3(2, 1536), 256, 0, stream>>>(A);
    k5_inv_wd<<<NVOL, 256, 0, stream>>>(A, x, out);
}

// Round 4
// 847.586 us; speedup vs baseline: 1.5298x; 1.0303x over previous
//
#include <hip/hip_runtime.h>
#include <math.h>

// AFNO-3D: rfftn(32^3, ortho) -> blockdiag complex MLP (8 x 96x96, GELU, softshrink) -> irfftn + residual
// B=2, C=768 (8 blocks x 96), H=W=D=32, Dr=17. kept==Dr -> no truncation.
//
// Round 4: spectrum buffer A stored as bf16x2 (4 B/complex) for all legs whose consumer
// already staged at bf16 (bit-identical: rounding moved producer-side). Inverse-H (k2i)
// emits split hi/lo planes (hi in-place lower half, lo upper half of the 214 MB ws) so
// k5 keeps full split precision with zero extra traffic vs fp32. k1 does 2 planes/block
// (it was latency-bound: HBM 22%, MFMA 13%, VALU 26% — nothing saturated).

#define CH    768
#define DR    17
#define PLANE 544            // 32*17 (kw,kd) plane elements
#define NVOL  49152          // B*C*H = 2*768*32
#define CSTRIDE 17408        // 32*PLANE, per-channel complex elements
#define NTOT  26738688       // NVOL*PLANE total spectrum elements
#define ORTHO 0.0055242717280199026f   // 1/sqrt(32768)
#define TWOPI_32 0.19634954084936207f  // 2*pi/32

typedef __bf16 bf16x8 __attribute__((ext_vector_type(8)));
typedef __bf16 bf16x2 __attribute__((ext_vector_type(2)));
typedef float  f32x4  __attribute__((ext_vector_type(4)));

#define MFMA __builtin_amdgcn_mfma_f32_16x16x32_bf16

__device__ __forceinline__ float gelu_f(float v) {
    return 0.5f * v * (1.0f + erff(v * 0.7071067811865475f));
}
__device__ __forceinline__ float sshrink(float v) {
    float a = fabsf(v) - 0.01f;
    return a > 0.f ? copysignf(a, v) : 0.f;
}
__device__ __forceinline__ bf16x8 ld8(const __bf16* p) { return *(const bf16x8*)p; }
// split v into bf16 hi + bf16 lo (~17 mantissa bits through a 3-product MFMA)
__device__ __forceinline__ void split2(float v, __bf16* h, __bf16* l) {
    __bf16 hh = (__bf16)v;
    *h = hh;
    *l = (__bf16)(v - (float)hh);
}

// Precomputed split-bf16 twiddle tables (identical for every block):
// gEf = e^{-2pi i rc/32}: [0]=cos_h [1]=cos_l [2]=sin_h [3]=sin_l
// gEb = e^{+2pi i rc/32};  gC = hermitian-folded inverse-D weights
__device__ __align__(16) __bf16 gEf[4][1024];
__device__ __align__(16) __bf16 gEb[4][1024];
__device__ __align__(16) __bf16 gC [4][1024];

__global__ void k0_tables() {
    int idx = blockIdx.x * 256 + threadIdx.x;
    if (idx >= 1024) return;
    int c = idx & 31;
    int r = idx >> 5;
    float ang = TWOPI_32 * (float)((r * c) & 31);
    float s, co; sincosf(ang, &s, &co);
    __bf16 h, l;
    split2(co, &h, &l);  gEf[0][idx] = h; gEf[1][idx] = l;
                         gEb[0][idx] = h; gEb[1][idx] = l;
    split2(-s, &h, &l);  gEf[2][idx] = h; gEf[3][idx] = l;
    split2(s, &h, &l);   gEb[2][idx] = h; gEb[3][idx] = l;
    float cf = (c == 0 || c == 16) ? 1.f : (c < DR ? 2.f : 0.f);
    split2(cf * co, &h, &l); gC[0][idx] = h; gC[1][idx] = l;
    split2(-cf * s, &h, &l); gC[2][idx] = h; gC[3][idx] = l;
}

// Precomputed bf16 transposed weights: [n][o][i], row stride 96 els = 192 B (16B-aligned)
__device__ __align__(16) __bf16 gW1r[73728], gW1i[73728], gW2r[73728], gW2i[73728];

__global__ void k0w(const float* __restrict__ w1r, const float* __restrict__ w1i,
                    const float* __restrict__ w2r, const float* __restrict__ w2i) {
    int idx = blockIdx.x * 256 + threadIdx.x;      // idx = (n*96 + o)*96 + i  (write-coalesced)
    if (idx >= 73728) return;
    int i = idx % 96, no = idx / 96;
    int o = no % 96, n = no / 96;
    int src = n * 9216 + i * 96 + o;
    gW1r[idx] = (__bf16)w1r[src];
    gW1i[idx] = (__bf16)w1i[src];
    gW2r[idx] = (__bf16)w2r[src];
    gW2i[idx] = (__bf16)w2i[src];
}

// ---------------- K1: forward D (real->17) + W DFT, 2 planes per block, split-bf16 MFMA ----------------
__global__ __launch_bounds__(256) void k1_fwd_dw(const float* __restrict__ x,
                                                 bf16x2* __restrict__ A) {
    __shared__ __align__(16) __bf16 sArh[2][32][40], sArl[2][32][40], sAih[2][32][40], sAil[2][32][40];
    const int t = threadIdx.x;
    const int wave = t >> 6, lane = t & 63, row = lane & 15, quad = lane >> 4;
    const int m0 = (wave >> 1) * 16, n0 = (wave & 1) * 16;
    const size_t pb = (size_t)blockIdx.x * 2048;

    // x fragments for both planes (issued before any compute)
    bf16x8 xh[2], xl[2];
    #pragma unroll
    for (int pl = 0; pl < 2; pl++) {
        const float* xp = x + pb + pl * 1024 + (size_t)(m0 + row) * 32 + quad * 8;
        f32x4 x0 = *(const f32x4*)xp;
        f32x4 x1 = *(const f32x4*)(xp + 4);
        #pragma unroll
        for (int j = 0; j < 4; j++) { __bf16 h = (__bf16)x0[j]; xh[pl][j] = h; xl[pl][j] = (__bf16)(x0[j] - (float)h); }
        #pragma unroll
        for (int j = 0; j < 4; j++) { __bf16 h = (__bf16)x1[j]; xh[pl][4+j] = h; xl[pl][4+j] = (__bf16)(x1[j] - (float)h); }
    }

    // ---- D-stage (both planes, shared E fragments) ----
    {
        const int ed = (n0 + row) * 32 + quad * 8;   // E[kd][d]
        bf16x8 erh = *(const bf16x8*)&gEf[0][ed];
        bf16x8 erl = *(const bf16x8*)&gEf[1][ed];
        bf16x8 eih = *(const bf16x8*)&gEf[2][ed];
        bf16x8 eil = *(const bf16x8*)&gEf[3][ed];
        #pragma unroll
        for (int pl = 0; pl < 2; pl++) {
            f32x4 ar = {0.f,0.f,0.f,0.f}, ai = {0.f,0.f,0.f,0.f};
            ar = MFMA(xh[pl], erh, ar, 0,0,0); ar = MFMA(xh[pl], erl, ar, 0,0,0); ar = MFMA(xl[pl], erh, ar, 0,0,0);
            ai = MFMA(xh[pl], eih, ai, 0,0,0); ai = MFMA(xh[pl], eil, ai, 0,0,0); ai = MFMA(xl[pl], eih, ai, 0,0,0);
            #pragma unroll
            for (int r4 = 0; r4 < 4; r4++) {
                int w = m0 + quad * 4 + r4, kd = n0 + row;
                split2(ar[r4], &sArh[pl][kd][w], &sArl[pl][kd][w]);
                split2(ai[r4], &sAih[pl][kd][w], &sAil[pl][kd][w]);
            }
        }
    }
    __syncthreads();
    // ---- W-stage (both planes, shared E fragments) ----
    {
        const int ew = (m0 + row) * 32 + quad * 8;   // E[kw][w]
        bf16x8 frh = *(const bf16x8*)&gEf[0][ew];
        bf16x8 frl = *(const bf16x8*)&gEf[1][ew];
        bf16x8 fih = *(const bf16x8*)&gEf[2][ew];
        bf16x8 fil = *(const bf16x8*)&gEf[3][ew];
        const int kd = n0 + row;
        #pragma unroll
        for (int pl = 0; pl < 2; pl++) {
            bf16x8 arh = ld8(&sArh[pl][n0 + row][quad * 8]);
            bf16x8 arl = ld8(&sArl[pl][n0 + row][quad * 8]);
            bf16x8 aih = ld8(&sAih[pl][n0 + row][quad * 8]);
            bf16x8 ail = ld8(&sAil[pl][n0 + row][quad * 8]);
            f32x4 rp = {0.f,0.f,0.f,0.f}, rm = {0.f,0.f,0.f,0.f}, im = {0.f,0.f,0.f,0.f};
            rp = MFMA(frh, arh, rp, 0,0,0); rp = MFMA(frh, arl, rp, 0,0,0); rp = MFMA(frl, arh, rp, 0,0,0);
            rm = MFMA(fih, aih, rm, 0,0,0); rm = MFMA(fih, ail, rm, 0,0,0); rm = MFMA(fil, aih, rm, 0,0,0);
            im = MFMA(frh, aih, im, 0,0,0); im = MFMA(frh, ail, im, 0,0,0); im = MFMA(frl, aih, im, 0,0,0);
            im = MFMA(fih, arh, im, 0,0,0); im = MFMA(fih, arl, im, 0,0,0); im = MFMA(fil, arh, im, 0,0,0);
            if (kd < DR) {
                const size_t ab = ((size_t)blockIdx.x * 2 + pl) * PLANE;
                #pragma unroll
                for (int r4 = 0; r4 < 4; r4++) {
                    int kw = m0 + quad * 4 + r4;
                    bf16x2 o;
                    o.x = (__bf16)((rp[r4] - rm[r4]) * ORTHO);
                    o.y = (__bf16)(im[r4] * ORTHO);
                    A[ab + kw * DR + kd] = o;
                }
            }
        }
    }
}

// ---------------- K2: H-axis complex DFT via bf16 MFMA ----------------
// forward (INV=0): bf16x2 in -> bf16x2 out (in-place).
// inverse (INV=1): bf16x2 in -> split hi (in-place) + lo (upper half of ws).
template <bool INV>
__global__ __launch_bounds__(256) void k2_fft_h(bf16x2* __restrict__ A) {
    __shared__ __align__(16) __bf16 sBr[272][40], sBi[272][40];  // B^T operand [p][h]
    const int t = threadIdx.x;
    const int p0g = blockIdx.x * 272;
    const size_t cb = (size_t)blockIdx.y * CSTRIDE;
    for (int idx = t; idx < 8704; idx += 256) {
        int h = idx / 272, p = idx - h * 272;
        bf16x2 v = A[cb + (size_t)h * PLANE + p0g + p];
        sBr[p][h] = v.x;
        sBi[p][h] = v.y;
    }
    __syncthreads();
    const int wave = t >> 6, lane = t & 63, row = lane & 15, quad = lane >> 4;
    const __bf16* Er = gEf[0];
    const __bf16* Ei = INV ? gEb[2] : gEf[2];
    bf16x8 er0 = *(const bf16x8*)&Er[row * 32 + quad * 8];
    bf16x8 ei0 = *(const bf16x8*)&Ei[row * 32 + quad * 8];
    bf16x8 er1 = *(const bf16x8*)&Er[(16 + row) * 32 + quad * 8];
    bf16x8 ei1 = *(const bf16x8*)&Ei[(16 + row) * 32 + quad * 8];
    for (int j = wave; j < 34; j += 4) {     // 2 M-tiles x 17 N-tiles
        int mt = j & 1, nt = j >> 1;
        int m0 = mt * 16, n0 = nt * 16;
        bf16x8 ar = mt ? er1 : er0;
        bf16x8 ai = mt ? ei1 : ei0;
        bf16x8 br = ld8(&sBr[n0 + row][quad * 8]);
        bf16x8 bi = ld8(&sBi[n0 + row][quad * 8]);
        f32x4 rp = {0.f,0.f,0.f,0.f}, rm = {0.f,0.f,0.f,0.f}, im = {0.f,0.f,0.f,0.f};
        rp = MFMA(ar, br, rp, 0, 0, 0);
        rm = MFMA(ai, bi, rm, 0, 0, 0);
        im = MFMA(ar, bi, im, 0, 0, 0);
        im = MFMA(ai, br, im, 0, 0, 0);
        int p = p0g + n0 + row;
        #pragma unroll
        for (int r = 0; r < 4; r++) {
            int kh = m0 + quad * 4 + r;
            size_t oidx = cb + (size_t)kh * PLANE + p;
            if (!INV) {
                bf16x2 o;
                o.x = (__bf16)(rp[r] - rm[r]);
                o.y = (__bf16)im[r];
                A[oidx] = o;
            } else {
                __bf16 rh, rl, ih, il;
                split2(rp[r] - rm[r], &rh, &rl);
                split2(im[r], &ih, &il);
                bf16x2 oh; oh.x = rh; oh.y = ih;
                bf16x2 ol; ol.x = rl; ol.y = il;
                A[oidx] = oh;
                A[NTOT + oidx] = ol;
            }
        }
    }
}

// ---------------- K3: block-diagonal complex MLP via bf16 MFMA, in-place ----------------
__global__ __launch_bounds__(256) void k3_mix(bf16x2* __restrict__ A,
    const float* __restrict__ b1r, const float* __restrict__ b1i,
    const float* __restrict__ b2r, const float* __restrict__ b2i) {
    __shared__ __align__(16) __bf16 sXr[64][104], sXi[64][104];  // B^T operand: [p][i]
    const int t = threadIdx.x;
    const int chunk = blockIdx.x, bn = blockIdx.y;
    const int b = bn >> 3, n = bn & 7;
    const size_t base = (size_t)(b * CH + n * 96) * CSTRIDE + chunk * 64;

    for (int idx = t; idx < 6144; idx += 256) {
        int i = idx >> 6, p = idx & 63;
        bf16x2 v = A[base + (size_t)i * CSTRIDE + p];
        sXr[p][i] = v.x;
        sXi[p][i] = v.y;
    }
    __syncthreads();

    const int wave = t >> 6, lane = t & 63, row = lane & 15, quad = lane >> 4;
    const __bf16* W1r = &gW1r[n * 9216];
    const __bf16* W1i = &gW1i[n * 9216];
    const __bf16* W2r = &gW2r[n * 9216];
    const __bf16* W2i = &gW2i[n * 9216];
    float h1s[6][8];

    #pragma unroll
    for (int q = 0; q < 6; q++) {
        int job = wave * 6 + q, mt = job >> 2, nt = job & 3;
        int m0 = mt * 16, p0 = nt * 16;
        f32x4 rp = {0.f,0.f,0.f,0.f}, rm = {0.f,0.f,0.f,0.f}, im = {0.f,0.f,0.f,0.f};
        #pragma unroll
        for (int ks = 0; ks < 3; ks++) {
            int k0 = ks * 32 + quad * 8;
            bf16x8 ar = ld8(&W1r[(m0 + row) * 96 + k0]);
            bf16x8 ai = ld8(&W1i[(m0 + row) * 96 + k0]);
            bf16x8 br = ld8(&sXr[p0 + row][k0]);
            bf16x8 bi = ld8(&sXi[p0 + row][k0]);
            rp = MFMA(ar, br, rp, 0, 0, 0);
            rm = MFMA(ai, bi, rm, 0, 0, 0);
            im = MFMA(ar, bi, im, 0, 0, 0);
            im = MFMA(ai, br, im, 0, 0, 0);
        }
        #pragma unroll
        for (int r = 0; r < 4; r++) {
            int o = m0 + quad * 4 + r;
            float hr = b1r[n * 96 + o] + rp[r] - rm[r];
            float hi = b1i[n * 96 + o] + im[r];
            h1s[q][r]     = gelu_f(hr);
            h1s[q][4 + r] = gelu_f(hi);
        }
    }
    __syncthreads();   // all waves done reading sX

    #pragma unroll
    for (int q = 0; q < 6; q++) {
        int job = wave * 6 + q, mt = job >> 2, nt = job & 3;
        int m0 = mt * 16, p0 = nt * 16;
        int p = p0 + row;
        #pragma unroll
        for (int r = 0; r < 4; r++) {
            int o = m0 + quad * 4 + r;
            sXr[p][o] = (__bf16)h1s[q][r];
            sXi[p][o] = (__bf16)h1s[q][4 + r];
        }
    }
    __syncthreads();

    #pragma unroll
    for (int q = 0; q < 6; q++) {
        int job = wave * 6 + q, mt = job >> 2, nt = job & 3;
        int m0 = mt * 16, p0 = nt * 16;
        f32x4 rp = {0.f,0.f,0.f,0.f}, rm = {0.f,0.f,0.f,0.f}, im = {0.f,0.f,0.f,0.f};
        #pragma unroll
        for (int ks = 0; ks < 3; ks++) {
            int k0 = ks * 32 + quad * 8;
            bf16x8 ar = ld8(&W2r[(m0 + row) * 96 + k0]);
            bf16x8 ai = ld8(&W2i[(m0 + row) * 96 + k0]);
            bf16x8 br = ld8(&sXr[p0 + row][k0]);
            bf16x8 bi = ld8(&sXi[p0 + row][k0]);
            rp = MFMA(ar, br, rp, 0, 0, 0);
            rm = MFMA(ai, bi, rm, 0, 0, 0);
            im = MFMA(ar, bi, im, 0, 0, 0);
            im = MFMA(ai, br, im, 0, 0, 0);
        }
        int p = p0 + row;
        #pragma unroll
        for (int r = 0; r < 4; r++) {
            int o = m0 + quad * 4 + r;
            bf16x2 oV;
            oV.x = (__bf16)sshrink(b2r[n * 96 + o] + rp[r] - rm[r]);
            oV.y = (__bf16)sshrink(b2i[n * 96 + o] + im[r]);
            A[base + (size_t)o * CSTRIDE + p] = oV;
        }
    }
}

// ---------------- K5: inverse W DFT + inverse real D DFT + residual, split-bf16 MFMA ----------------
__global__ __launch_bounds__(256) void k5_inv_wd(const bf16x2* __restrict__ A,
                                                 const float* __restrict__ x,
                                                 float* __restrict__ out) {
    // Z (stage-1 B^T [kd][kw]) and G (stage-2 A [w][kd]) alias the same buffers.
    __shared__ __align__(16) __bf16 sZrh[32][40], sZrl[32][40], sZih[32][40], sZil[32][40];
    const int t = threadIdx.x;
    const int wave = t >> 6, lane = t & 63, row = lane & 15, quad = lane >> 4;
    const int m0 = (wave >> 1) * 16, n0 = (wave & 1) * 16;
    const size_t ab = (size_t)blockIdx.x * PLANE;
    const size_t pb = (size_t)blockIdx.x * 1024;
    const int d = n0 + row;

    float xres[4];
    #pragma unroll
    for (int r4 = 0; r4 < 4; r4++)
        xres[r4] = x[pb + (size_t)(m0 + quad * 4 + r4) * 32 + d];

    // hi/lo planes precomputed by k2_fft_h<true>; direct copy into LDS, no VALU split
    for (int idx = t; idx < PLANE; idx += 256) {
        int kw = idx / DR, kd = idx - kw * DR;
        bf16x2 h = A[ab + idx];
        bf16x2 l = A[NTOT + ab + idx];
        sZrh[kd][kw] = h.x; sZrl[kd][kw] = l.x;
        sZih[kd][kw] = h.y; sZil[kd][kw] = l.y;
    }
    for (int idx = t; idx < 480; idx += 256) {
        int kd = DR + (idx >> 5), kw = idx & 31;
        sZrh[kd][kw] = (__bf16)0.f; sZrl[kd][kw] = (__bf16)0.f;
        sZih[kd][kw] = (__bf16)0.f; sZil[kd][kw] = (__bf16)0.f;
    }
    __syncthreads();

    // ---- stage 1: complex W-inverse ----
    const int e1 = (m0 + row) * 32 + quad * 8;       // E+[w][kw]
    bf16x8 erh = *(const bf16x8*)&gEb[0][e1];
    bf16x8 erl = *(const bf16x8*)&gEb[1][e1];
    bf16x8 eih = *(const bf16x8*)&gEb[2][e1];
    bf16x8 eil = *(const bf16x8*)&gEb[3][e1];
    bf16x8 zrh = ld8(&sZrh[n0 + row][quad * 8]);
    bf16x8 zrl = ld8(&sZrl[n0 + row][quad * 8]);
    bf16x8 zih = ld8(&sZih[n0 + row][quad * 8]);
    bf16x8 zil = ld8(&sZil[n0 + row][quad * 8]);
    f32x4 rp = {0.f,0.f,0.f,0.f}, rm = {0.f,0.f,0.f,0.f}, im = {0.f,0.f,0.f,0.f};
    rp = MFMA(erh, zrh, rp, 0,0,0); rp = MFMA(erh, zrl, rp, 0,0,0); rp = MFMA(erl, zrh, rp, 0,0,0);
    rm = MFMA(eih, zih, rm, 0,0,0); rm = MFMA(eih, zil, rm, 0,0,0); rm = MFMA(eil, zih, rm, 0,0,0);
    im = MFMA(erh, zih, im, 0,0,0); im = MFMA(erh, zil, im, 0,0,0); im = MFMA(erl, zih, im, 0,0,0);
    im = MFMA(eih, zrh, im, 0,0,0); im = MFMA(eih, zrl, im, 0,0,0); im = MFMA(eil, zrh, im, 0,0,0);
    __syncthreads();   // all Z reads complete block-wide before overwrite as G
    #pragma unroll
    for (int r4 = 0; r4 < 4; r4++) {
        int w = m0 + quad * 4 + r4, kd = n0 + row;
        split2(rp[r4] - rm[r4], &sZrh[w][kd], &sZrl[w][kd]);   // now holds G[w][kd]
        split2(im[r4],          &sZih[w][kd], &sZil[w][kd]);
    }
    __syncthreads();

    // ---- stage 2: real D-inverse + residual ----
    const int c2 = d * 32 + quad * 8;                // C[d][kd]
    bf16x8 crh = *(const bf16x8*)&gC[0][c2];
    bf16x8 crl = *(const bf16x8*)&gC[1][c2];
    bf16x8 cih = *(const bf16x8*)&gC[2][c2];
    bf16x8 cil = *(const bf16x8*)&gC[3][c2];
    bf16x8 grh = ld8(&sZrh[m0 + row][quad * 8]);
    bf16x8 grl = ld8(&sZrl[m0 + row][quad * 8]);
    bf16x8 gih = ld8(&sZih[m0 + row][quad * 8]);
    bf16x8 gil = ld8(&sZil[m0 + row][quad * 8]);
    f32x4 acc = {0.f,0.f,0.f,0.f};
    acc = MFMA(grh, crh, acc, 0,0,0); acc = MFMA(grh, crl, acc, 0,0,0); acc = MFMA(grl, crh, acc, 0,0,0);
    acc = MFMA(gih, cih, acc, 0,0,0); acc = MFMA(gih, cil, acc, 0,0,0); acc = MFMA(gil, cih, acc, 0,0,0);
    #pragma unroll
    for (int r4 = 0; r4 < 4; r4++) {
        int w = m0 + quad * 4 + r4;
        out[pb + (size_t)w * 32 + d] = acc[r4] * ORTHO + xres[r4];
    }
}

extern "C" void kernel_launch(void* const* d_in, const int* in_sizes, int n_in,
                              void* d_out, int out_size, void* d_ws, size_t ws_size,
                              hipStream_t stream) {
    const float* x   = (const float*)d_in[0];
    const float* w1r = (const float*)d_in[1];
    const float* w1i = (const float*)d_in[2];
    const float* w2r = (const float*)d_in[3];
    const float* w2i = (const float*)d_in[4];
    const float* b1r = (const float*)d_in[5];
    const float* b1i = (const float*)d_in[6];
    const float* b2r = (const float*)d_in[7];
    const float* b2i = (const float*)d_in[8];
    float* out = (float*)d_out;
    bf16x2* A = (bf16x2*)d_ws;   // 2*NTOT*4 B = 214 MB: [0,NTOT) main/hi plane, [NTOT,2*NTOT) lo plane

    k0_tables<<<4, 256, 0, stream>>>();
    k0w<<<288, 256, 0, stream>>>(w1r, w1i, w2r, w2i);
    k1_fwd_dw<<<NVOL / 2, 256, 0, stream>>>(x, A);
    k2_fft_h<false><<<dim3(2, 1536), 256, 0, stream>>>(A);
    k3_mix<<<dim3(272, 16), 256, 0, stream>>>(A, b1r, b1i, b2r, b2i);
    k2_fft_h<true><<<dim3(2, 1536), 256, 0, stream>>>(A);
    k5_inv_wd<<<NVOL, 256, 0, stream>>>(A, x, out);
}

// Round 7
// 808.414 us; speedup vs baseline: 1.6039x; 1.0485x over previous
//
#include <hip/hip_runtime.h>
#include <math.h>

// AFNO-3D: rfftn(32^3, ortho) -> blockdiag complex MLP (8 x 96x96, GELU, softshrink) -> irfftn + residual
// B=2, C=768 (8 blocks x 96), H=W=D=32, Dr=17. kept==Dr -> no truncation.
//
// Round 7: rounds 5/6 failed with no kernel error; only untested novelty was k3's
// 161/135 KB static LDS. k3 redesigned to the PROVEN 66,560 B footprint (round-2's
// exact LDS size): W1 staged once via linear bf16x8 copies from pre-transposed gW
// (no fp32 transpose/cvt), layer-1 LDS-fed, W2 overwrites the same buffer during
// h1 writeback, layer-2 LDS-fed. Fixes round-4's L2-latency exposure (per-q global
// W loads) with zero unproven allocation sizes. k1 4-plane (41 KB), k5 2-plane
// (20 KB), bf16x2 spectrum + split hi/lo emit from k2i — all as audited in r5/6.

#define CH    768
#define DR    17
#define PLANE 544            // 32*17 (kw,kd) plane elements
#define NVOL  49152          // B*C*H = 2*768*32
#define CSTRIDE 17408        // 32*PLANE, per-channel complex elements
#define NTOT  26738688       // NVOL*PLANE total spectrum elements
#define ORTHO 0.0055242717280199026f   // 1/sqrt(32768)
#define TWOPI_32 0.19634954084936207f  // 2*pi/32

typedef __bf16 bf16x8 __attribute__((ext_vector_type(8)));
typedef __bf16 bf16x2 __attribute__((ext_vector_type(2)));
typedef float  f32x4  __attribute__((ext_vector_type(4)));

#define MFMA __builtin_amdgcn_mfma_f32_16x16x32_bf16

__device__ __forceinline__ float gelu_f(float v) {
    return 0.5f * v * (1.0f + erff(v * 0.7071067811865475f));
}
__device__ __forceinline__ float sshrink(float v) {
    float a = fabsf(v) - 0.01f;
    return a > 0.f ? copysignf(a, v) : 0.f;
}
__device__ __forceinline__ bf16x8 ld8(const __bf16* p) { return *(const bf16x8*)p; }
// split v into bf16 hi + bf16 lo (~17 mantissa bits through a 3-product MFMA)
__device__ __forceinline__ void split2(float v, __bf16* h, __bf16* l) {
    __bf16 hh = (__bf16)v;
    *h = hh;
    *l = (__bf16)(v - (float)hh);
}

// Precomputed split-bf16 twiddle tables (identical for every block):
__device__ __align__(16) __bf16 gEf[4][1024];
__device__ __align__(16) __bf16 gEb[4][1024];
__device__ __align__(16) __bf16 gC [4][1024];

__global__ void k0_tables() {
    int idx = blockIdx.x * 256 + threadIdx.x;
    if (idx >= 1024) return;
    int c = idx & 31;
    int r = idx >> 5;
    float ang = TWOPI_32 * (float)((r * c) & 31);
    float s, co; sincosf(ang, &s, &co);
    __bf16 h, l;
    split2(co, &h, &l);  gEf[0][idx] = h; gEf[1][idx] = l;
                         gEb[0][idx] = h; gEb[1][idx] = l;
    split2(-s, &h, &l);  gEf[2][idx] = h; gEf[3][idx] = l;
    split2(s, &h, &l);   gEb[2][idx] = h; gEb[3][idx] = l;
    float cf = (c == 0 || c == 16) ? 1.f : (c < DR ? 2.f : 0.f);
    split2(cf * co, &h, &l); gC[0][idx] = h; gC[1][idx] = l;
    split2(-cf * s, &h, &l); gC[2][idx] = h; gC[3][idx] = l;
}

// Precomputed bf16 transposed weights: [n][o][i], row stride 96 els = 192 B (16B-aligned)
__device__ __align__(16) __bf16 gW1r[73728], gW1i[73728], gW2r[73728], gW2i[73728];

__global__ void k0w(const float* __restrict__ w1r, const float* __restrict__ w1i,
                    const float* __restrict__ w2r, const float* __restrict__ w2i) {
    int idx = blockIdx.x * 256 + threadIdx.x;
    if (idx >= 73728) return;
    int i = idx % 96, no = idx / 96;
    int o = no % 96, n = no / 96;
    int src = n * 9216 + i * 96 + o;
    gW1r[idx] = (__bf16)w1r[src];
    gW1i[idx] = (__bf16)w1i[src];
    gW2r[idx] = (__bf16)w2r[src];
    gW2i[idx] = (__bf16)w2i[src];
}

// ---------------- K1: forward D (real->17) + W DFT, 4 planes per block ----------------
__global__ __launch_bounds__(256) void k1_fwd_dw(const float* __restrict__ x,
                                                 bf16x2* __restrict__ A) {
    __shared__ __align__(16) __bf16 sArh[4][32][40], sArl[4][32][40], sAih[4][32][40], sAil[4][32][40];
    const int t = threadIdx.x;
    const int wave = t >> 6, lane = t & 63, row = lane & 15, quad = lane >> 4;
    const int m0 = (wave >> 1) * 16, n0 = (wave & 1) * 16;
    const size_t pb = (size_t)blockIdx.x * 4096;

    bf16x8 xh[4], xl[4];
    #pragma unroll
    for (int pl = 0; pl < 4; pl++) {
        const float* xp = x + pb + pl * 1024 + (size_t)(m0 + row) * 32 + quad * 8;
        f32x4 x0 = *(const f32x4*)xp;
        f32x4 x1 = *(const f32x4*)(xp + 4);
        #pragma unroll
        for (int j = 0; j < 4; j++) { __bf16 h = (__bf16)x0[j]; xh[pl][j] = h; xl[pl][j] = (__bf16)(x0[j] - (float)h); }
        #pragma unroll
        for (int j = 0; j < 4; j++) { __bf16 h = (__bf16)x1[j]; xh[pl][4+j] = h; xl[pl][4+j] = (__bf16)(x1[j] - (float)h); }
    }

    // ---- D-stage (all planes, shared E fragments) ----
    {
        const int ed = (n0 + row) * 32 + quad * 8;   // E[kd][d]
        bf16x8 erh = *(const bf16x8*)&gEf[0][ed];
        bf16x8 erl = *(const bf16x8*)&gEf[1][ed];
        bf16x8 eih = *(const bf16x8*)&gEf[2][ed];
        bf16x8 eil = *(const bf16x8*)&gEf[3][ed];
        #pragma unroll
        for (int pl = 0; pl < 4; pl++) {
            f32x4 ar = {0.f,0.f,0.f,0.f}, ai = {0.f,0.f,0.f,0.f};
            ar = MFMA(xh[pl], erh, ar, 0,0,0); ar = MFMA(xh[pl], erl, ar, 0,0,0); ar = MFMA(xl[pl], erh, ar, 0,0,0);
            ai = MFMA(xh[pl], eih, ai, 0,0,0); ai = MFMA(xh[pl], eil, ai, 0,0,0); ai = MFMA(xl[pl], eih, ai, 0,0,0);
            #pragma unroll
            for (int r4 = 0; r4 < 4; r4++) {
                int w = m0 + quad * 4 + r4, kd = n0 + row;
                split2(ar[r4], &sArh[pl][kd][w], &sArl[pl][kd][w]);
                split2(ai[r4], &sAih[pl][kd][w], &sAil[pl][kd][w]);
            }
        }
    }
    __syncthreads();
    // ---- W-stage (all planes, shared E fragments) ----
    {
        const int ew = (m0 + row) * 32 + quad * 8;   // E[kw][w]
        bf16x8 frh = *(const bf16x8*)&gEf[0][ew];
        bf16x8 frl = *(const bf16x8*)&gEf[1][ew];
        bf16x8 fih = *(const bf16x8*)&gEf[2][ew];
        bf16x8 fil = *(const bf16x8*)&gEf[3][ew];
        const int kd = n0 + row;
        #pragma unroll
        for (int pl = 0; pl < 4; pl++) {
            bf16x8 arh = ld8(&sArh[pl][n0 + row][quad * 8]);
            bf16x8 arl = ld8(&sArl[pl][n0 + row][quad * 8]);
            bf16x8 aih = ld8(&sAih[pl][n0 + row][quad * 8]);
            bf16x8 ail = ld8(&sAil[pl][n0 + row][quad * 8]);
            f32x4 rp = {0.f,0.f,0.f,0.f}, rm = {0.f,0.f,0.f,0.f}, im = {0.f,0.f,0.f,0.f};
            rp = MFMA(frh, arh, rp, 0,0,0); rp = MFMA(frh, arl, rp, 0,0,0); rp = MFMA(frl, arh, rp, 0,0,0);
            rm = MFMA(fih, aih, rm, 0,0,0); rm = MFMA(fih, ail, rm, 0,0,0); rm = MFMA(fil, aih, rm, 0,0,0);
            im = MFMA(frh, aih, im, 0,0,0); im = MFMA(frh, ail, im, 0,0,0); im = MFMA(frl, aih, im, 0,0,0);
            im = MFMA(fih, arh, im, 0,0,0); im = MFMA(fih, arl, im, 0,0,0); im = MFMA(fil, arh, im, 0,0,0);
            if (kd < DR) {
                const size_t ab = ((size_t)blockIdx.x * 4 + pl) * PLANE;
                #pragma unroll
                for (int r4 = 0; r4 < 4; r4++) {
                    int kw = m0 + quad * 4 + r4;
                    bf16x2 o;
                    o.x = (__bf16)((rp[r4] - rm[r4]) * ORTHO);
                    o.y = (__bf16)(im[r4] * ORTHO);
                    A[ab + kw * DR + kd] = o;
                }
            }
        }
    }
}

// ---------------- K2: H-axis complex DFT via bf16 MFMA ----------------
// forward (INV=0): bf16x2 in -> bf16x2 out (in-place).
// inverse (INV=1): bf16x2 in -> split hi (in-place) + lo (upper half of ws).
template <bool INV>
__global__ __launch_bounds__(256) void k2_fft_h(bf16x2* __restrict__ A) {
    __shared__ __align__(16) __bf16 sBr[272][40], sBi[272][40];  // B^T operand [p][h]
    const int t = threadIdx.x;
    const int p0g = blockIdx.x * 272;
    const size_t cb = (size_t)blockIdx.y * CSTRIDE;
    for (int idx = t; idx < 8704; idx += 256) {
        int h = idx / 272, p = idx - h * 272;
        bf16x2 v = A[cb + (size_t)h * PLANE + p0g + p];
        sBr[p][h] = v.x;
        sBi[p][h] = v.y;
    }
    __syncthreads();
    const int wave = t >> 6, lane = t & 63, row = lane & 15, quad = lane >> 4;
    const __bf16* Er = gEf[0];
    const __bf16* Ei = INV ? gEb[2] : gEf[2];
    bf16x8 er0 = *(const bf16x8*)&Er[row * 32 + quad * 8];
    bf16x8 ei0 = *(const bf16x8*)&Ei[row * 32 + quad * 8];
    bf16x8 er1 = *(const bf16x8*)&Er[(16 + row) * 32 + quad * 8];
    bf16x8 ei1 = *(const bf16x8*)&Ei[(16 + row) * 32 + quad * 8];
    for (int j = wave; j < 34; j += 4) {     // 2 M-tiles x 17 N-tiles
        int mt = j & 1, nt = j >> 1;
        int m0 = mt * 16, n0 = nt * 16;
        bf16x8 ar = mt ? er1 : er0;
        bf16x8 ai = mt ? ei1 : ei0;
        bf16x8 br = ld8(&sBr[n0 + row][quad * 8]);
        bf16x8 bi = ld8(&sBi[n0 + row][quad * 8]);
        f32x4 rp = {0.f,0.f,0.f,0.f}, rm = {0.f,0.f,0.f,0.f}, im = {0.f,0.f,0.f,0.f};
        rp = MFMA(ar, br, rp, 0, 0, 0);
        rm = MFMA(ai, bi, rm, 0, 0, 0);
        im = MFMA(ar, bi, im, 0, 0, 0);
        im = MFMA(ai, br, im, 0, 0, 0);
        int p = p0g + n0 + row;
        #pragma unroll
        for (int r = 0; r < 4; r++) {
            int kh = m0 + quad * 4 + r;
            size_t oidx = cb + (size_t)kh * PLANE + p;
            if (!INV) {
                bf16x2 o;
                o.x = (__bf16)(rp[r] - rm[r]);
                o.y = (__bf16)im[r];
                A[oidx] = o;
            } else {
                __bf16 rh, rl, ih, il;
                split2(rp[r] - rm[r], &rh, &rl);
                split2(im[r], &ih, &il);
                bf16x2 oh; oh.x = rh; oh.y = ih;
                bf16x2 ol; ol.x = rl; ol.y = il;
                A[oidx] = oh;
                A[NTOT + oidx] = ol;
            }
        }
    }
}

// ---------------- K3: block-diagonal complex MLP — LDS-staged W (66,560 B, proven size) ----------------
// Grid dim3(272, 16), 256 threads (round-4 proven dispatch). W1 staged once via linear
// bf16x8 copies from gW; W2 overwrites the same buffer during h1 writeback. Inner loops
// are pure LDS+MFMA (no global latency between MFMAs — round-4's diagnosed stall).
__global__ __launch_bounds__(256) void k3_mix(bf16x2* __restrict__ A,
    const float* __restrict__ b1r, const float* __restrict__ b1i,
    const float* __restrict__ b2r, const float* __restrict__ b2i) {
    __shared__ __align__(16) __bf16 sWr[96][104], sWi[96][104];  // 39,936 B (A-operand [o][i])
    __shared__ __align__(16) __bf16 sXr[64][104], sXi[64][104];  // 26,624 B (B^T [p][i]; reused for h1)
    const int t = threadIdx.x;
    const int chunk = blockIdx.x, bn = blockIdx.y;
    const int b = bn >> 3, n = bn & 7;
    const size_t base = (size_t)(b * CH + n * 96) * CSTRIDE + chunk * 64;

    // stage W1 (linear bf16x8 copies; j*8 = row*96 + off*8)
    for (int j = t; j < 1152; j += 256) {
        int rw = j / 12, off = j - rw * 12;
        *(bf16x8*)&sWr[rw][off * 8] = *(const bf16x8*)&gW1r[n * 9216 + j * 8];
        *(bf16x8*)&sWi[rw][off * 8] = *(const bf16x8*)&gW1i[n * 9216 + j * 8];
    }
    // stage X^T [p][i]
    for (int idx = t; idx < 6144; idx += 256) {
        int i = idx >> 6, p = idx & 63;
        bf16x2 v = A[base + (size_t)i * CSTRIDE + p];
        sXr[p][i] = v.x;
        sXi[p][i] = v.y;
    }
    __syncthreads();

    const int wave = t >> 6, lane = t & 63, row = lane & 15, quad = lane >> 4;
    float h1s[6][8];

    // ---- layer 1: 6 M-tiles x 4 N-tiles = 24 jobs, 6 per wave ----
    #pragma unroll
    for (int q = 0; q < 6; q++) {
        int job = wave * 6 + q, mt = job >> 2, nt = job & 3;
        int m0 = mt * 16, p0 = nt * 16;
        f32x4 rp = {0.f,0.f,0.f,0.f}, rm = {0.f,0.f,0.f,0.f}, im = {0.f,0.f,0.f,0.f};
        #pragma unroll
        for (int ks = 0; ks < 3; ks++) {
            int k0 = ks * 32 + quad * 8;
            bf16x8 ar = ld8(&sWr[m0 + row][k0]);
            bf16x8 ai = ld8(&sWi[m0 + row][k0]);
            bf16x8 br = ld8(&sXr[p0 + row][k0]);
            bf16x8 bi = ld8(&sXi[p0 + row][k0]);
            rp = MFMA(ar, br, rp, 0, 0, 0);
            rm = MFMA(ai, bi, rm, 0, 0, 0);
            im = MFMA(ar, bi, im, 0, 0, 0);
            im = MFMA(ai, br, im, 0, 0, 0);
        }
        #pragma unroll
        for (int r = 0; r < 4; r++) {
            int o = m0 + quad * 4 + r;
            float hr = b1r[n * 96 + o] + rp[r] - rm[r];
            float hi = b1i[n * 96 + o] + im[r];
            h1s[q][r]     = gelu_f(hr);
            h1s[q][4 + r] = gelu_f(hi);
        }
    }
    __syncthreads();   // all waves done reading sW (W1) and sX (X)

    // write h1 into sX (B^T [p][o]) and overwrite sW with W2
    #pragma unroll
    for (int q = 0; q < 6; q++) {
        int job = wave * 6 + q, mt = job >> 2, nt = job & 3;
        int m0 = mt * 16, p0 = nt * 16;
        int p = p0 + row;
        #pragma unroll
        for (int r = 0; r < 4; r++) {
            int o = m0 + quad * 4 + r;
            sXr[p][o] = (__bf16)h1s[q][r];
            sXi[p][o] = (__bf16)h1s[q][4 + r];
        }
    }
    for (int j = t; j < 1152; j += 256) {
        int rw = j / 12, off = j - rw * 12;
        *(bf16x8*)&sWr[rw][off * 8] = *(const bf16x8*)&gW2r[n * 9216 + j * 8];
        *(bf16x8*)&sWi[rw][off * 8] = *(const bf16x8*)&gW2i[n * 9216 + j * 8];
    }
    __syncthreads();

    // ---- layer 2 + softshrink + store ----
    #pragma unroll
    for (int q = 0; q < 6; q++) {
        int job = wave * 6 + q, mt = job >> 2, nt = job & 3;
        int m0 = mt * 16, p0 = nt * 16;
        f32x4 rp = {0.f,0.f,0.f,0.f}, rm = {0.f,0.f,0.f,0.f}, im = {0.f,0.f,0.f,0.f};
        #pragma unroll
        for (int ks = 0; ks < 3; ks++) {
            int k0 = ks * 32 + quad * 8;
            bf16x8 ar = ld8(&sWr[m0 + row][k0]);
            bf16x8 ai = ld8(&sWi[m0 + row][k0]);
            bf16x8 br = ld8(&sXr[p0 + row][k0]);
            bf16x8 bi = ld8(&sXi[p0 + row][k0]);
            rp = MFMA(ar, br, rp, 0, 0, 0);
            rm = MFMA(ai, bi, rm, 0, 0, 0);
            im = MFMA(ar, bi, im, 0, 0, 0);
            im = MFMA(ai, br, im, 0, 0, 0);
        }
        int p = p0 + row;
        #pragma unroll
        for (int r = 0; r < 4; r++) {
            int o = m0 + quad * 4 + r;
            bf16x2 oV;
            oV.x = (__bf16)sshrink(b2r[n * 96 + o] + rp[r] - rm[r]);
            oV.y = (__bf16)sshrink(b2i[n * 96 + o] + im[r]);
            A[base + (size_t)o * CSTRIDE + p] = oV;
        }
    }
}

// ---------------- K5: inverse W DFT + inverse real D DFT + residual, 2 planes per block ----------------
__global__ __launch_bounds__(256) void k5_inv_wd(const bf16x2* __restrict__ A,
                                                 const float* __restrict__ x,
                                                 float* __restrict__ out) {
    // Z (stage-1 B^T [kd][kw]) and G (stage-2 A [w][kd]) alias the same buffers, per plane.
    __shared__ __align__(16) __bf16 sZrh[2][32][40], sZrl[2][32][40], sZih[2][32][40], sZil[2][32][40];
    const int t = threadIdx.x;
    const int wave = t >> 6, lane = t & 63, row = lane & 15, quad = lane >> 4;
    const int m0 = (wave >> 1) * 16, n0 = (wave & 1) * 16;
    const size_t ab = (size_t)blockIdx.x * (2 * PLANE);
    const size_t pb = (size_t)blockIdx.x * 2048;
    const int d = n0 + row;

    float xres[2][4];
    #pragma unroll
    for (int pl = 0; pl < 2; pl++)
        #pragma unroll
        for (int r4 = 0; r4 < 4; r4++)
            xres[pl][r4] = x[pb + pl * 1024 + (size_t)(m0 + quad * 4 + r4) * 32 + d];

    // hi/lo planes precomputed by k2_fft_h<true>
    for (int idx = t; idx < 2 * PLANE; idx += 256) {
        int pl = idx / PLANE, li = idx - pl * PLANE;
        int kw = li / DR, kd = li - kw * DR;
        bf16x2 h = A[ab + idx];
        bf16x2 l = A[NTOT + ab + idx];
        sZrh[pl][kd][kw] = h.x; sZrl[pl][kd][kw] = l.x;
        sZih[pl][kd][kw] = h.y; sZil[pl][kd][kw] = l.y;
    }
    for (int idx = t; idx < 960; idx += 256) {
        int pl = idx / 480, r = idx - pl * 480;
        int kd = DR + (r >> 5), kw = r & 31;
        sZrh[pl][kd][kw] = (__bf16)0.f; sZrl[pl][kd][kw] = (__bf16)0.f;
        sZih[pl][kd][kw] = (__bf16)0.f; sZil[pl][kd][kw] = (__bf16)0.f;
    }
    __syncthreads();

    // ---- stage 1: complex W-inverse (both planes, shared E fragments) ----
    const int e1 = (m0 + row) * 32 + quad * 8;       // E+[w][kw]
    bf16x8 erh = *(const bf16x8*)&gEb[0][e1];
    bf16x8 erl = *(const bf16x8*)&gEb[1][e1];
    bf16x8 eih = *(const bf16x8*)&gEb[2][e1];
    bf16x8 eil = *(const bf16x8*)&gEb[3][e1];
    f32x4 s1r[2], s1i[2];
    #pragma unroll
    for (int pl = 0; pl < 2; pl++) {
        bf16x8 zrh = ld8(&sZrh[pl][n0 + row][quad * 8]);
        bf16x8 zrl = ld8(&sZrl[pl][n0 + row][quad * 8]);
        bf16x8 zih = ld8(&sZih[pl][n0 + row][quad * 8]);
        bf16x8 zil = ld8(&sZil[pl][n0 + row][quad * 8]);
        f32x4 rp = {0.f,0.f,0.f,0.f}, rm = {0.f,0.f,0.f,0.f}, im = {0.f,0.f,0.f,0.f};
        rp = MFMA(erh, zrh, rp, 0,0,0); rp = MFMA(erh, zrl, rp, 0,0,0); rp = MFMA(erl, zrh, rp, 0,0,0);
        rm = MFMA(eih, zih, rm, 0,0,0); rm = MFMA(eih, zil, rm, 0,0,0); rm = MFMA(eil, zih, rm, 0,0,0);
        im = MFMA(erh, zih, im, 0,0,0); im = MFMA(erh, zil, im, 0,0,0); im = MFMA(erl, zih, im, 0,0,0);
        im = MFMA(eih, zrh, im, 0,0,0); im = MFMA(eih, zrl, im, 0,0,0); im = MFMA(eil, zrh, im, 0,0,0);
        s1r[pl] = rp - rm;
        s1i[pl] = im;
    }
    __syncthreads();   // all Z reads complete block-wide before overwrite as G
    #pragma unroll
    for (int pl = 0; pl < 2; pl++) {
        #pragma unroll
        for (int r4 = 0; r4 < 4; r4++) {
            int w = m0 + quad * 4 + r4, kd = n0 + row;
            split2(s1r[pl][r4], &sZrh[pl][w][kd], &sZrl[pl][w][kd]);   // now holds G[w][kd]
            split2(s1i[pl][r4], &sZih[pl][w][kd], &sZil[pl][w][kd]);
        }
    }
    __syncthreads();

    // ---- stage 2: real D-inverse + residual (both planes, shared C fragments) ----
    const int c2 = d * 32 + quad * 8;                // C[d][kd]
    bf16x8 crh = *(const bf16x8*)&gC[0][c2];
    bf16x8 crl = *(const bf16x8*)&gC[1][c2];
    bf16x8 cih = *(const bf16x8*)&gC[2][c2];
    bf16x8 cil = *(const bf16x8*)&gC[3][c2];
    #pragma unroll
    for (int pl = 0; pl < 2; pl++) {
        bf16x8 grh = ld8(&sZrh[pl][m0 + row][quad * 8]);
        bf16x8 grl = ld8(&sZrl[pl][m0 + row][quad * 8]);
        bf16x8 gih = ld8(&sZih[pl][m0 + row][quad * 8]);
        bf16x8 gil = ld8(&sZil[pl][m0 + row][quad * 8]);
        f32x4 acc = {0.f,0.f,0.f,0.f};
        acc = MFMA(grh, crh, acc, 0,0,0); acc = MFMA(grh, crl, acc, 0,0,0); acc = MFMA(grl, crh, acc, 0,0,0);
        acc = MFMA(gih, cih, acc, 0,0,0); acc = MFMA(gih, cil, acc, 0,0,0); acc = MFMA(gil, cih, acc, 0,0,0);
        #pragma unroll
        for (int r4 = 0; r4 < 4; r4++) {
            int w = m0 + quad * 4 + r4;
            out[pb + pl * 1024 + (size_t)w * 32 + d] = acc[r4] * ORTHO + xres[pl][r4];
        }
    }
}

extern "C" void kernel_launch(void* const* d_in, const int* in_sizes, int n_in,
                              void* d_out, int out_size, void* d_ws, size_t ws_size,
                              hipStream_t stream) {
    const float* x   = (const float*)d_in[0];
    const float* w1r = (const float*)d_in[1];
    const float* w1i = (const float*)d_in[2];
    const float* w2r = (const float*)d_in[3];
    const float* w2i = (const float*)d_in[4];
    const float* b1r = (const float*)d_in[5];
    const float* b1i = (const float*)d_in[6];
    const float* b2r = (const float*)d_in[7];
    const float* b2i = (const float*)d_in[8];
    float* out = (float*)d_out;
    bf16x2* A = (bf16x2*)d_ws;   // 2*NTOT*4 B = 214 MB: [0,NTOT) main/hi plane, [NTOT,2*NTOT) lo plane

    k0_tables<<<4, 256, 0, stream>>>();
    k0w<<<288, 256, 0, stream>>>(w1r, w1i, w2r, w2i);
    k1_fwd_dw<<<NVOL / 4, 256, 0, stream>>>(x, A);
    k2_fft_h<false><<<dim3(2, 1536), 256, 0, stream>>>(A);
    k3_mix<<<dim3(272, 16), 256, 0, stream>>>(A, b1r, b1i, b2r, b2i);
    k2_fft_h<true><<<dim3(2, 1536), 256, 0, stream>>>(A);
    k5_inv_wd<<<NVOL / 2, 256, 0, stream>>>(A, x, out);
}